// Round 18
// baseline (276.739 us; speedup 1.0000x reference)
//
#include <hip/hip_runtime.h>
#include <hip/hip_bf16.h>
#include <math.h>

typedef __hip_bfloat16 bft;
typedef __attribute__((ext_vector_type(8))) short bf16x8;
typedef __attribute__((ext_vector_type(4))) float f32x4;

constexpr int cB = 2, cS = 2048, cD = 1024, cH = 16, cHKV = 4, cGQ = 4, cHD = 64;
constexpr int cBS = 32, cTB = 16, cNB = 64, cNC = 127;

#define GL16(gp, lp) __builtin_amdgcn_global_load_lds((const __attribute__((address_space(1))) void*)(gp), (__attribute__((address_space(3))) void*)(lp), 16, 0, 0)
#define FENCE asm volatile("" ::: "memory")

__device__ __forceinline__ float bf2f(short h) {
    return __uint_as_float(((unsigned int)(unsigned short)h) << 16);
}

// ---------------- transpose + fp32->bf16 convert: src[K][N] -> dst[N][K] ----------------
__global__ void k_transpose_cvt(const float* __restrict__ src, bft* __restrict__ dst, int K, int N) {
    __shared__ float tile[32][33];
    int kb = blockIdx.x * 32, nb = blockIdx.y * 32;
    int tx = threadIdx.x, ty = threadIdx.y; // 32 x 8
    #pragma unroll
    for (int i = 0; i < 32; i += 8) {
        int k = kb + ty + i, n = nb + tx;
        tile[ty + i][tx] = (k < K && n < N) ? src[(size_t)k * N + n] : 0.f;
    }
    __syncthreads();
    #pragma unroll
    for (int i = 0; i < 32; i += 8) {
        int n = nb + ty + i, k = kb + tx;
        if (n < N && k < K) dst[(size_t)n * K + k] = __float2bfloat16(tile[tx][ty + i]);
    }
}

// ---------------- fused QKVG weight transpose: wcat[1664][1024] from wq/wk/wv/wg (+zero pad) ----------------
__global__ void k_transpose_qkvg(const float* __restrict__ wq, const float* __restrict__ wk,
                                 const float* __restrict__ wv, const float* __restrict__ wg,
                                 bft* __restrict__ dst) {
    __shared__ float tile[32][33];
    int kb = blockIdx.x * 32, nb = blockIdx.y * 32;   // nb in [0,1664)
    const float* src; int N, off;
    if (nb < 1024)      { src = wq; N = 1024; off = 0; }
    else if (nb < 1280) { src = wk; N = 256;  off = 1024; }
    else if (nb < 1536) { src = wv; N = 256;  off = 1280; }
    else                { src = wg; N = 48;   off = 1536; }
    int tx = threadIdx.x, ty = threadIdx.y; // 32 x 8
    #pragma unroll
    for (int i = 0; i < 32; i += 8) {
        int k = kb + ty + i, n = nb - off + tx;
        tile[ty + i][tx] = (n < N) ? src[(size_t)k * N + n] : 0.f;
    }
    __syncthreads();
    #pragma unroll
    for (int i = 0; i < 32; i += 8) {
        int n = nb + ty + i, k = kb + tx;
        dst[(size_t)n * 1024 + k] = __float2bfloat16(tile[tx][ty + i]);
    }
}

// ---------------- LayerNorm (fp32 in, bf16 out) ----------------
__global__ __launch_bounds__(256) void k_ln(const float* __restrict__ src, const float* __restrict__ w,
                                            const float* __restrict__ b, bft* __restrict__ dst) {
    int row = blockIdx.x; int t = threadIdx.x;
    const float4* xr = (const float4*)(src + (size_t)row * cD);
    float4 v = xr[t];
    float s = v.x + v.y + v.z + v.w;
    #pragma unroll
    for (int o = 32; o; o >>= 1) s += __shfl_xor(s, o);
    __shared__ float red[8];
    int wid = t >> 6, lane = t & 63;
    if (lane == 0) red[wid] = s;
    __syncthreads();
    float mean = (red[0] + red[1] + red[2] + red[3]) * (1.f / cD);
    float dx = v.x - mean, dy = v.y - mean, dz = v.z - mean, dw = v.w - mean;
    float sq = dx * dx + dy * dy + dz * dz + dw * dw;
    #pragma unroll
    for (int o = 32; o; o >>= 1) sq += __shfl_xor(sq, o);
    if (lane == 0) red[4 + wid] = sq;
    __syncthreads();
    float var = (red[4] + red[5] + red[6] + red[7]) * (1.f / cD);
    float rstd = rsqrtf(var + 1e-5f);
    float4 wv = ((const float4*)w)[t];
    float4 bv = ((const float4*)b)[t];
    bft* o_ = dst + (size_t)row * cD + t * 4;
    o_[0] = __float2bfloat16(dx * rstd * wv.x + bv.x);
    o_[1] = __float2bfloat16(dy * rstd * wv.y + bv.y);
    o_[2] = __float2bfloat16(dz * rstd * wv.z + bv.z);
    o_[3] = __float2bfloat16(dw * rstd * wv.w + bv.w);
}

// ---------------- MFMA GEMM 128^2 (m97 structure + XCD swizzle): C = A * Bt^T ----------------
template<int MODE>
__global__ __launch_bounds__(256) void k_gemm(const bft* __restrict__ A, const bft* __restrict__ Bt,
        int M, int N, int K,
        const float* __restrict__ bias, const float* __restrict__ add,
        float* __restrict__ outf, bft* __restrict__ outb,
        float* __restrict__ oq, float* __restrict__ okk, float* __restrict__ ovv, float* __restrict__ og,
        const float* __restrict__ bq, const float* __restrict__ bk,
        const float* __restrict__ bv, const float* __restrict__ bg,
        bft* __restrict__ oqb) {
    __shared__ __align__(16) bft As[128 * 64];
    __shared__ __align__(16) bft Bs[128 * 64];
    int tid = threadIdx.x;
    int nwg = gridDim.x * gridDim.y;
    int bid = blockIdx.y * gridDim.x + blockIdx.x;
    int q8 = nwg >> 3;
    int wg = (bid & 7) * q8 + (bid >> 3);
    int bx = wg % gridDim.x, by = wg / gridDim.x;
    int m0 = by * 128, n0 = bx * 128;
    int lane = tid & 63, wid = tid >> 6;
    int wr = wid >> 1, wc = wid & 1;
    int lrow = lane & 15, lk = lane >> 4;
    f32x4 acc[4][4];
    #pragma unroll
    for (int i = 0; i < 4; ++i)
        #pragma unroll
        for (int j = 0; j < 4; ++j) acc[i][j] = (f32x4)0.f;

    for (int kt = 0; kt < K; kt += 64) {
        #pragma unroll
        for (int sh = 0; sh < 4; ++sh) {
            int p = sh * 256 + tid;
            int row = p >> 3;
            int slot = p & 7;
            int ss = slot ^ (row & 7);
            const bft* ga = A + (size_t)(m0 + row) * K + kt + ss * 8;
            const bft* gb = Bt + (size_t)(n0 + row) * K + kt + ss * 8;
            GL16(ga, (char*)As + p * 16);
            GL16(gb, (char*)Bs + p * 16);
        }
        __syncthreads();
        #pragma unroll
        for (int kh = 0; kh < 2; ++kh) {
            bf16x8 af[4], bfv[4];
            #pragma unroll
            for (int mi = 0; mi < 4; ++mi) {
                int row = wr * 64 + mi * 16 + lrow;
                int c8 = kh * 4 + lk;
                af[mi] = *(const bf16x8*)((const char*)As + row * 128 + ((c8 ^ (row & 7)) * 16));
            }
            #pragma unroll
            for (int ni = 0; ni < 4; ++ni) {
                int row = wc * 64 + ni * 16 + lrow;
                int c8 = kh * 4 + lk;
                bfv[ni] = *(const bf16x8*)((const char*)Bs + row * 128 + ((c8 ^ (row & 7)) * 16));
            }
            #pragma unroll
            for (int mi = 0; mi < 4; ++mi)
                #pragma unroll
                for (int ni = 0; ni < 4; ++ni)
                    acc[mi][ni] = __builtin_amdgcn_mfma_f32_16x16x32_bf16(af[mi], bfv[ni], acc[mi][ni], 0, 0, 0);
        }
        __syncthreads();
    }
    #pragma unroll
    for (int mi = 0; mi < 4; ++mi)
        #pragma unroll
        for (int ni = 0; ni < 4; ++ni)
            #pragma unroll
            for (int r = 0; r < 4; ++r) {
                int gr = m0 + wr * 64 + mi * 16 + lk * 4 + r;
                int gc = n0 + wc * 64 + ni * 16 + lrow;
                float val = acc[mi][ni][r];
                if (MODE == 0) {
                    if (gc < 1024) {
                        float qv2 = val + bq[gc];
                        oq[(size_t)gr * 1024 + gc] = qv2;
                        oqb[(size_t)gr * 1024 + gc] = __float2bfloat16(qv2 * 0.125f);
                    }
                    else if (gc < 1280) okk[(size_t)gr * 256 + gc - 1024] = val + bk[gc - 1024];
                    else if (gc < 1536) ovv[(size_t)gr * 256 + gc - 1280] = val + bv[gc - 1280];
                    else if (gc < 1584) {
                        float t2 = val + bg[gc - 1536];
                        og[(size_t)gr * 48 + gc - 1536] = 1.f / (1.f + __expf(-t2));
                    }
                } else if (MODE == 1) {
                    size_t o = (size_t)gr * N + gc;
                    outf[o] = val + bias[gc] + add[o];
                } else if (MODE == 2) {
                    float t2 = val + bias[gc];
                    float ge = 0.5f * t2 * (1.f + erff(t2 * 0.70710678118654752f));
                    outb[(size_t)gr * N + gc] = __float2bfloat16(ge);
                } else {
                    size_t o = (size_t)gr * N + gc;
                    outf[o] = val + bias[gc] + add[o];
                }
            }
}

// ---------------- 256^2 8-phase GEMM (T2+T3+T4+T5), fused GELU: zbuf = gelu(hbuf @ w1T^T + b1) ----------------
__global__ __launch_bounds__(512) void k_gemm256_gelu(const bft* __restrict__ A, const bft* __restrict__ Bt,
                                                      const float* __restrict__ bias, bft* __restrict__ outb) {
    constexpr int K = 1024, N = 4096, NT = K / 64;
    __shared__ __align__(16) bft As[2][256 * 64];
    __shared__ __align__(16) bft Bs[2][256 * 64];
    int tid = threadIdx.x;
    int nwg = gridDim.x * gridDim.y;                 // 256
    int bid = blockIdx.y * gridDim.x + blockIdx.x;
    int q8 = nwg >> 3;
    int wg = (bid & 7) * q8 + (bid >> 3);            // bijective XCD swizzle
    int bx = wg % gridDim.x, by = wg / gridDim.x;
    int m0 = by * 256, n0 = bx * 256;
    int w = tid >> 6, lane = tid & 63, lrow = lane & 15, lk = lane >> 4;
    int wr = w >> 2, wc = w & 3;
    int l8 = lane >> 3, l7 = lane & 7;
    int ssrc = (l7 ^ l8) * 8;

    auto stageA = [&](int buf, int h, int kt) {
        int rbase = 32 * w + 16 * h;
        const bft* g0 = A + (size_t)(m0 + rbase + l8) * K + kt + ssrc;
        GL16(g0, (char*)As[buf] + rbase * 128 + lane * 16);
        const bft* g1 = A + (size_t)(m0 + rbase + 8 + l8) * K + kt + ssrc;
        GL16(g1, (char*)As[buf] + rbase * 128 + 1024 + lane * 16);
    };
    auto stageB = [&](int buf, int h, int kt) {
        int rbase = 32 * w + 16 * h;
        const bft* g0 = Bt + (size_t)(n0 + rbase + l8) * K + kt + ssrc;
        GL16(g0, (char*)Bs[buf] + rbase * 128 + lane * 16);
        const bft* g1 = Bt + (size_t)(n0 + rbase + 8 + l8) * K + kt + ssrc;
        GL16(g1, (char*)Bs[buf] + rbase * 128 + 1024 + lane * 16);
    };
    auto ldA = [&](int buf, int mi, int kk) {
        int r = wr * 128 + mi * 16 + lrow;
        return *(const bf16x8*)((const char*)As[buf] + r * 128 + (((kk * 4 + lk) ^ (r & 7)) * 16));
    };
    auto ldB = [&](int buf, int ni, int kk) {
        int r = wc * 64 + ni * 16 + lrow;
        return *(const bf16x8*)((const char*)Bs[buf] + r * 128 + (((kk * 4 + lk) ^ (r & 7)) * 16));
    };

    f32x4 acc[8][4];
    #pragma unroll
    for (int i = 0; i < 8; ++i)
        #pragma unroll
        for (int j = 0; j < 4; ++j) acc[i][j] = (f32x4)0.f;

    stageA(0, 0, 0); stageB(0, 0, 0); stageA(0, 1, 0); stageB(0, 1, 0);
    asm volatile("s_waitcnt vmcnt(4)" ::: "memory");
    FENCE; __builtin_amdgcn_s_barrier(); FENCE;

    bf16x8 aE[4][2], aO[4][2], bE[2][2], bO[2][2];
    for (int t = 0; t < NT; ++t) {
        int cur = t & 1, nxt = cur ^ 1;
        int ktn = (t + 1) * 64;
        bool pre = (t + 1 < NT);
        #pragma unroll
        for (int i = 0; i < 4; ++i)
            #pragma unroll
            for (int kk = 0; kk < 2; ++kk) aE[i][kk] = ldA(cur, 2 * i, kk);
        #pragma unroll
        for (int j = 0; j < 2; ++j)
            #pragma unroll
            for (int kk = 0; kk < 2; ++kk) bE[j][kk] = ldB(cur, 2 * j, kk);
        if (pre) { stageA(nxt, 0, ktn); asm volatile("s_waitcnt vmcnt(2)" ::: "memory"); }
        else     {                       asm volatile("s_waitcnt vmcnt(0)" ::: "memory"); }
        FENCE; __builtin_amdgcn_s_barrier(); FENCE;
        __builtin_amdgcn_s_setprio(1);
        #pragma unroll
        for (int i = 0; i < 4; ++i)
            #pragma unroll
            for (int j = 0; j < 2; ++j)
                #pragma unroll
                for (int kk = 0; kk < 2; ++kk)
                    acc[2 * i][2 * j] = __builtin_amdgcn_mfma_f32_16x16x32_bf16(aE[i][kk], bE[j][kk], acc[2 * i][2 * j], 0, 0, 0);
        __builtin_amdgcn_s_setprio(0);
        FENCE; __builtin_amdgcn_s_barrier(); FENCE;
        #pragma unroll
        for (int j = 0; j < 2; ++j)
            #pragma unroll
            for (int kk = 0; kk < 2; ++kk) bO[j][kk] = ldB(cur, 2 * j + 1, kk);
        if (pre) stageB(nxt, 0, ktn);
        FENCE; __builtin_amdgcn_s_barrier(); FENCE;
        __builtin_amdgcn_s_setprio(1);
        #pragma unroll
        for (int i = 0; i < 4; ++i)
            #pragma unroll
            for (int j = 0; j < 2; ++j)
                #pragma unroll
                for (int kk = 0; kk < 2; ++kk)
                    acc[2 * i][2 * j + 1] = __builtin_amdgcn_mfma_f32_16x16x32_bf16(aE[i][kk], bO[j][kk], acc[2 * i][2 * j + 1], 0, 0, 0);
        __builtin_amdgcn_s_setprio(0);
        FENCE; __builtin_amdgcn_s_barrier(); FENCE;
        #pragma unroll
        for (int i = 0; i < 4; ++i)
            #pragma unroll
            for (int kk = 0; kk < 2; ++kk) aO[i][kk] = ldA(cur, 2 * i + 1, kk);
        if (pre) stageA(nxt, 1, ktn);
        FENCE; __builtin_amdgcn_s_barrier(); FENCE;
        __builtin_amdgcn_s_setprio(1);
        #pragma unroll
        for (int i = 0; i < 4; ++i)
            #pragma unroll
            for (int j = 0; j < 2; ++j)
                #pragma unroll
                for (int kk = 0; kk < 2; ++kk)
                    acc[2 * i + 1][2 * j] = __builtin_amdgcn_mfma_f32_16x16x32_bf16(aO[i][kk], bE[j][kk], acc[2 * i + 1][2 * j], 0, 0, 0);
        __builtin_amdgcn_s_setprio(0);
        FENCE; __builtin_amdgcn_s_barrier(); FENCE;
        if (pre) { stageB(nxt, 1, ktn); asm volatile("s_waitcnt vmcnt(4)" ::: "memory"); }
        FENCE; __builtin_amdgcn_s_barrier(); FENCE;
        __builtin_amdgcn_s_setprio(1);
        #pragma unroll
        for (int i = 0; i < 4; ++i)
            #pragma unroll
            for (int j = 0; j < 2; ++j)
                #pragma unroll
                for (int kk = 0; kk < 2; ++kk)
                    acc[2 * i + 1][2 * j + 1] = __builtin_amdgcn_mfma_f32_16x16x32_bf16(aO[i][kk], bO[j][kk], acc[2 * i + 1][2 * j + 1], 0, 0, 0);
        __builtin_amdgcn_s_setprio(0);
        FENCE; __builtin_amdgcn_s_barrier(); FENCE;
    }
    #pragma unroll
    for (int mi = 0; mi < 8; ++mi)
        #pragma unroll
        for (int ni = 0; ni < 4; ++ni)
            #pragma unroll
            for (int r = 0; r < 4; ++r) {
                int gr = m0 + wr * 128 + mi * 16 + lk * 4 + r;
                int gc = n0 + wc * 64 + ni * 16 + lrow;
                float t2 = acc[mi][ni][r] + bias[gc];
                float ge = 0.5f * t2 * (1.f + erff(t2 * 0.70710678118654752f));
                outb[(size_t)gr * N + gc] = __float2bfloat16(ge);
            }
}

// ---------------- 256^2 8-phase split-K GEMM for MLP-down: partials = zbuf @ w2T^T (bf16) ----------------
__global__ __launch_bounds__(512) void k_gemm256_sk(const bft* __restrict__ A, const bft* __restrict__ Bt,
                                                    bft* __restrict__ q0, bft* __restrict__ q1,
                                                    bft* __restrict__ q2, bft* __restrict__ q3) {
    constexpr int KT = 4096, N = 1024, NT = 16;
    __shared__ __align__(16) bft As[2][256 * 64];
    __shared__ __align__(16) bft Bs[2][256 * 64];
    int tid = threadIdx.x;
    int flat = blockIdx.x;
    int wg = (flat & 7) * 32 + (flat >> 3);          // bijective XCD swizzle over 256
    int slice = wg >> 6; int rem = wg & 63;
    int m0 = (rem >> 2) * 256, n0 = (rem & 3) * 256;
    int kbase = slice * 1024;
    int w = tid >> 6, lane = tid & 63, lrow = lane & 15, lk = lane >> 4;
    int wr = w >> 2, wc = w & 3;
    int l8 = lane >> 3, l7 = lane & 7;
    int ssrc = (l7 ^ l8) * 8;

    auto stageA = [&](int buf, int h, int kt) {
        int rbase = 32 * w + 16 * h;
        const bft* g0 = A + (size_t)(m0 + rbase + l8) * KT + kbase + kt + ssrc;
        GL16(g0, (char*)As[buf] + rbase * 128 + lane * 16);
        const bft* g1 = A + (size_t)(m0 + rbase + 8 + l8) * KT + kbase + kt + ssrc;
        GL16(g1, (char*)As[buf] + rbase * 128 + 1024 + lane * 16);
    };
    auto stageB = [&](int buf, int h, int kt) {
        int rbase = 32 * w + 16 * h;
        const bft* g0 = Bt + (size_t)(n0 + rbase + l8) * KT + kbase + kt + ssrc;
        GL16(g0, (char*)Bs[buf] + rbase * 128 + lane * 16);
        const bft* g1 = Bt + (size_t)(n0 + rbase + 8 + l8) * KT + kbase + kt + ssrc;
        GL16(g1, (char*)Bs[buf] + rbase * 128 + 1024 + lane * 16);
    };
    auto ldA = [&](int buf, int mi, int kk) {
        int r = wr * 128 + mi * 16 + lrow;
        return *(const bf16x8*)((const char*)As[buf] + r * 128 + (((kk * 4 + lk) ^ (r & 7)) * 16));
    };
    auto ldB = [&](int buf, int ni, int kk) {
        int r = wc * 64 + ni * 16 + lrow;
        return *(const bf16x8*)((const char*)Bs[buf] + r * 128 + (((kk * 4 + lk) ^ (r & 7)) * 16));
    };

    f32x4 acc[8][4];
    #pragma unroll
    for (int i = 0; i < 8; ++i)
        #pragma unroll
        for (int j = 0; j < 4; ++j) acc[i][j] = (f32x4)0.f;

    stageA(0, 0, 0); stageB(0, 0, 0); stageA(0, 1, 0); stageB(0, 1, 0);
    asm volatile("s_waitcnt vmcnt(4)" ::: "memory");
    FENCE; __builtin_amdgcn_s_barrier(); FENCE;

    bf16x8 aE[4][2], aO[4][2], bE[2][2], bO[2][2];
    for (int t = 0; t < NT; ++t) {
        int cur = t & 1, nxt = cur ^ 1;
        int ktn = (t + 1) * 64;
        bool pre = (t + 1 < NT);
        #pragma unroll
        for (int i = 0; i < 4; ++i)
            #pragma unroll
            for (int kk = 0; kk < 2; ++kk) aE[i][kk] = ldA(cur, 2 * i, kk);
        #pragma unroll
        for (int j = 0; j < 2; ++j)
            #pragma unroll
            for (int kk = 0; kk < 2; ++kk) bE[j][kk] = ldB(cur, 2 * j, kk);
        if (pre) { stageA(nxt, 0, ktn); asm volatile("s_waitcnt vmcnt(2)" ::: "memory"); }
        else     {                       asm volatile("s_waitcnt vmcnt(0)" ::: "memory"); }
        FENCE; __builtin_amdgcn_s_barrier(); FENCE;
        __builtin_amdgcn_s_setprio(1);
        #pragma unroll
        for (int i = 0; i < 4; ++i)
            #pragma unroll
            for (int j = 0; j < 2; ++j)
                #pragma unroll
                for (int kk = 0; kk < 2; ++kk)
                    acc[2 * i][2 * j] = __builtin_amdgcn_mfma_f32_16x16x32_bf16(aE[i][kk], bE[j][kk], acc[2 * i][2 * j], 0, 0, 0);
        __builtin_amdgcn_s_setprio(0);
        FENCE; __builtin_amdgcn_s_barrier(); FENCE;
        #pragma unroll
        for (int j = 0; j < 2; ++j)
            #pragma unroll
            for (int kk = 0; kk < 2; ++kk) bO[j][kk] = ldB(cur, 2 * j + 1, kk);
        if (pre) stageB(nxt, 0, ktn);
        FENCE; __builtin_amdgcn_s_barrier(); FENCE;
        __builtin_amdgcn_s_setprio(1);
        #pragma unroll
        for (int i = 0; i < 4; ++i)
            #pragma unroll
            for (int j = 0; j < 2; ++j)
                #pragma unroll
                for (int kk = 0; kk < 2; ++kk)
                    acc[2 * i][2 * j + 1] = __builtin_amdgcn_mfma_f32_16x16x32_bf16(aE[i][kk], bO[j][kk], acc[2 * i][2 * j + 1], 0, 0, 0);
        __builtin_amdgcn_s_setprio(0);
        FENCE; __builtin_amdgcn_s_barrier(); FENCE;
        #pragma unroll
        for (int i = 0; i < 4; ++i)
            #pragma unroll
            for (int kk = 0; kk < 2; ++kk) aO[i][kk] = ldA(cur, 2 * i + 1, kk);
        if (pre) stageA(nxt, 1, ktn);
        FENCE; __builtin_amdgcn_s_barrier(); FENCE;
        __builtin_amdgcn_s_setprio(1);
        #pragma unroll
        for (int i = 0; i < 4; ++i)
            #pragma unroll
            for (int j = 0; j < 2; ++j)
                #pragma unroll
                for (int kk = 0; kk < 2; ++kk)
                    acc[2 * i + 1][2 * j] = __builtin_amdgcn_mfma_f32_16x16x32_bf16(aO[i][kk], bE[j][kk], acc[2 * i + 1][2 * j], 0, 0, 0);
        __builtin_amdgcn_s_setprio(0);
        FENCE; __builtin_amdgcn_s_barrier(); FENCE;
        if (pre) { stageB(nxt, 1, ktn); asm volatile("s_waitcnt vmcnt(4)" ::: "memory"); }
        FENCE; __builtin_amdgcn_s_barrier(); FENCE;
        __builtin_amdgcn_s_setprio(1);
        #pragma unroll
        for (int i = 0; i < 4; ++i)
            #pragma unroll
            for (int j = 0; j < 2; ++j)
                #pragma unroll
                for (int kk = 0; kk < 2; ++kk)
                    acc[2 * i + 1][2 * j + 1] = __builtin_amdgcn_mfma_f32_16x16x32_bf16(aO[i][kk], bO[j][kk], acc[2 * i + 1][2 * j + 1], 0, 0, 0);
        __builtin_amdgcn_s_setprio(0);
        FENCE; __builtin_amdgcn_s_barrier(); FENCE;
    }
    bft* pp = (slice == 0) ? q0 : (slice == 1) ? q1 : (slice == 2) ? q2 : q3;
    #pragma unroll
    for (int mi = 0; mi < 8; ++mi)
        #pragma unroll
        for (int ni = 0; ni < 4; ++ni)
            #pragma unroll
            for (int r = 0; r < 4; ++r) {
                int gr = m0 + wr * 128 + mi * 16 + lk * 4 + r;
                int gc = n0 + wc * 64 + ni * 16 + lrow;
                pp[(size_t)gr * N + gc] = __float2bfloat16(acc[mi][ni][r]);
            }
}

// ---------------- split-K reduce: out = x1 + b2 + sum(partials) ----------------
__global__ __launch_bounds__(256) void k_mlpred(const bft* __restrict__ q0, const bft* __restrict__ q1,
                                                const bft* __restrict__ q2, const bft* __restrict__ q3,
                                                const float* __restrict__ x1, const float* __restrict__ b2,
                                                float* __restrict__ out) {
    size_t i = ((size_t)blockIdx.x * 256 + threadIdx.x) * 8;
    bf16x8 a0 = *(const bf16x8*)(q0 + i);
    bf16x8 a1 = *(const bf16x8*)(q1 + i);
    bf16x8 a2 = *(const bf16x8*)(q2 + i);
    bf16x8 a3 = *(const bf16x8*)(q3 + i);
    int col = (int)(i & 1023);
    float4 b0 = *(const float4*)(b2 + col);
    float4 b1v = *(const float4*)(b2 + col + 4);
    float4 x0 = *(const float4*)(x1 + i);
    float4 x1v = *(const float4*)(x1 + i + 4);
    float s[8];
    #pragma unroll
    for (int j = 0; j < 8; ++j)
        s[j] = bf2f(a0[j]) + bf2f(a1[j]) + bf2f(a2[j]) + bf2f(a3[j]);
    float4 o0 = make_float4(s[0] + b0.x + x0.x, s[1] + b0.y + x0.y, s[2] + b0.z + x0.z, s[3] + b0.w + x0.w);
    float4 o1 = make_float4(s[4] + b1v.x + x1v.x, s[5] + b1v.y + x1v.y, s[6] + b1v.z + x1v.z, s[7] + b1v.w + x1v.w);
    *(float4*)(out + i) = o0;
    *(float4*)(out + i + 4) = o1;
}

// ---------------- compressed K/V means -> bf16 ck [bk][128][64], transposed cvT [bk][64][128] ----------------
// 256 thr: 4 j-groups x 64 lanes, LDS tree-reduce (sync via __syncthreads only)
__global__ __launch_bounds__(256) void k_cmp_kv(const float* __restrict__ k, const float* __restrict__ v,
                                                bft* __restrict__ ck, bft* __restrict__ cvT) {
    __shared__ float redk[4][64], redv[4][64];
    int idx = blockIdx.x;
    int n = idx & 127; int bk = idx >> 7; int kv = bk & 3; int b = bk >> 2;
    int jg = threadIdx.x >> 6, d = threadIdx.x & 63;
    if (n == 127) {
        if (threadIdx.x < 64) {
            ck[(size_t)bk * 8192 + 127 * 64 + d] = __float2bfloat16(0.f);
            cvT[(size_t)bk * 8192 + d * 128 + 127] = __float2bfloat16(0.f);
        }
        return;
    }
    float sk = 0.f, sv = 0.f;
    int base = b * cS + n * 16 + jg * 8;
    #pragma unroll
    for (int j = 0; j < 8; ++j) {
        size_t o = (size_t)(base + j) * 256 + kv * 64 + d;
        sk += k[o]; sv += v[o];
    }
    redk[jg][d] = sk; redv[jg][d] = sv;
    __syncthreads();
    if (jg == 0) {
        float tk = redk[0][d] + redk[1][d] + redk[2][d] + redk[3][d];
        float tv = redv[0][d] + redv[1][d] + redv[2][d] + redv[3][d];
        ck[(size_t)bk * 8192 + n * 64 + d] = __float2bfloat16(tk * (1.f / 32.f));
        cvT[(size_t)bk * 8192 + d * 128 + n] = __float2bfloat16(tv * (1.f / 32.f));
    }
}

// ---------------- compressed attention, MFMA flash (reads pre-scaled qb16; writes att16c = bf16(g0*oc)) ----------------
__global__ __launch_bounds__(256) void k_cmp_attn(const bft* __restrict__ qb16, const bft* __restrict__ ck,
                                                  const bft* __restrict__ cvT, const float* __restrict__ gates,
                                                  bft* __restrict__ att) {
    __shared__ __align__(16) bft Qs[256 * 64];
    __shared__ __align__(16) bft Ks[128 * 64];
    __shared__ __align__(16) bft VTs[64 * 128];
    __shared__ __align__(16) bft Ps[4 * 16 * 128];
    int idx = blockIdx.x;
    int chunk = idx & 31; int bk = idx >> 5; int kv = bk & 3; int b = bk >> 2;
    int tid = threadIdx.x;
    // stage Q via GL16 from pre-scaled bf16 (pre-swizzled source); r in [0,256), hh in [0,4)
    #pragma unroll
    for (int c = 0; c < 8; ++c) {
        int p = c * 256 + tid; int r = p >> 3, s = p & 7;
        int hh = r >> 6, toff = r & 63;
        const bft* src = qb16 + ((size_t)(b * cS + chunk * 64 + toff)) * 1024 + (kv * 4 + hh) * 64 + ((s ^ (r & 7)) * 8);
        GL16(src, (char*)Qs + p * 16);
    }
    if (tid < 128) {
        int r = tid;
        const bf16x8* src = (const bf16x8*)(ck + (size_t)bk * 8192 + r * 64);
        #pragma unroll
        for (int s = 0; s < 8; ++s)
            *(bf16x8*)((char*)Ks + r * 128 + ((s ^ (r & 7)) * 16)) = src[s];
    }
    if (tid < 64) {
        int r = tid;
        const bf16x8* src = (const bf16x8*)(cvT + (size_t)bk * 8192 + r * 128);
        #pragma unroll
        for (int s = 0; s < 16; ++s)
            *(bf16x8*)((char*)VTs + r * 256 + ((s ^ (r & 7)) * 16)) = src[s];
    }
    __syncthreads();

    int w = tid >> 6, lane = tid & 63, lrow = lane & 15, lk = lane >> 4;
    int hg = kv * cGQ + w;
    #pragma unroll
    for (int rt = 0; rt < 4; ++rt) {
        int rowb = w * 64 + rt * 16;
        bf16x8 aq[2];
        #pragma unroll
        for (int kh = 0; kh < 2; ++kh) {
            int r = rowb + lrow;
            aq[kh] = *(const bf16x8*)((const char*)Qs + r * 128 + (((kh * 4 + lk) ^ (r & 7)) * 16));
        }
        f32x4 sa[8];
        #pragma unroll
        for (int nt = 0; nt < 8; ++nt) {
            sa[nt] = (f32x4)0.f;
            #pragma unroll
            for (int kh = 0; kh < 2; ++kh) {
                int kr = nt * 16 + lrow;
                bf16x8 bv_ = *(const bf16x8*)((const char*)Ks + kr * 128 + (((kh * 4 + lk) ^ (kr & 7)) * 16));
                sa[nt] = __builtin_amdgcn_mfma_f32_16x16x32_bf16(aq[kh], bv_, sa[nt], 0, 0, 0);
            }
        }
        float mrow[4], srow[4]; int nv[4];
        #pragma unroll
        for (int r = 0; r < 4; ++r) {
            int s_abs = chunk * 64 + rt * 16 + lk * 4 + r;
            nv[r] = (s_abs >= 31) ? (((s_abs - 31) >> 4) + 1) : 0;
            mrow[r] = -INFINITY; srow[r] = 0.f;
        }
        #pragma unroll
        for (int nt = 0; nt < 8; ++nt) {
            int key = nt * 16 + lrow;
            #pragma unroll
            for (int r = 0; r < 4; ++r) {
                float sc = sa[nt][r];   // qb16 pre-scaled by 1/8
                if (key < nv[r]) mrow[r] = fmaxf(mrow[r], sc);
            }
        }
        #pragma unroll
        for (int r = 0; r < 4; ++r) {
            #pragma unroll
            for (int o = 8; o; o >>= 1) mrow[r] = fmaxf(mrow[r], __shfl_xor(mrow[r], o));
        }
        #pragma unroll
        for (int nt = 0; nt < 8; ++nt) {
            int key = nt * 16 + lrow;
            #pragma unroll
            for (int r = 0; r < 4; ++r) {
                float sc = sa[nt][r];
                float p = (key < nv[r]) ? __expf(sc - mrow[r]) : 0.f;
                srow[r] += p;
                int rit = lk * 4 + r;
                *(bft*)((char*)Ps + w * 4096 + rit * 256 + ((((key >> 3) ^ (rit & 7))) * 16) + (key & 7) * 2) =
                    __float2bfloat16(p);
            }
        }
        #pragma unroll
        for (int r = 0; r < 4; ++r) {
            #pragma unroll
            for (int o = 8; o; o >>= 1) srow[r] += __shfl_xor(srow[r], o);
        }
        f32x4 oa[4];
        #pragma unroll
        for (int dt = 0; dt < 4; ++dt) oa[dt] = (f32x4)0.f;
        #pragma unroll
        for (int kc = 0; kc < 4; ++kc) {
            bf16x8 pa = *(const bf16x8*)((const char*)Ps + w * 4096 + lrow * 256 + (((kc * 4 + lk) ^ (lrow & 7)) * 16));
            #pragma unroll
            for (int dt = 0; dt < 4; ++dt) {
                int vr = dt * 16 + lrow;
                bf16x8 vb = *(const bf16x8*)((const char*)VTs + vr * 256 + (((kc * 4 + lk) ^ (vr & 7)) * 16));
                oa[dt] = __builtin_amdgcn_mfma_f32_16x16x32_bf16(pa, vb, oa[dt], 0, 0, 0);
            }
        }
        float inv[4]; int toks[4];
        #pragma unroll
        for (int r = 0; r < 4; ++r) {
            int tok = chunk * 64 + rt * 16 + lk * 4 + r;
            toks[r] = tok;
            float g0 = gates[((size_t)(b * cS + tok)) * 48 + hg * 3 + 0];
            inv[r] = (srow[r] > 0.f) ? (g0 / srow[r]) : 0.f;
        }
        #pragma unroll
        for (int dt = 0; dt < 4; ++dt)
            #pragma unroll
            for (int r = 0; r < 4; ++r)
                att[((size_t)(b * cS + toks[r])) * 1024 + hg * 64 + dt * 16 + lrow] = __float2bfloat16(oa[dt][r] * inv[r]);
    }
}

// ---------------- K/V -> bf16 (+V transpose) prep: kb16 [bkv][2048][64], vT16 [bkv][64][2048] ----------------
__global__ __launch_bounds__(256) void k_kvprep(const float* __restrict__ k, const float* __restrict__ v,
                                                bft* __restrict__ kb16, bft* __restrict__ vT16) {
    __shared__ float vt[64 * 65];
    int idx = blockIdx.x; int tc = idx & 31; int kv = (idx >> 5) & 3; int b = idx >> 7;
    int t = threadIdx.x; int ti = t >> 2, seg = t & 3, d0 = seg * 16;
    const float4* ks = (const float4*)(k + (size_t)(b * cS + tc * 64 + ti) * 256 + kv * 64 + d0);
    const float4* vs = (const float4*)(v + (size_t)(b * cS + tc * 64 + ti) * 256 + kv * 64 + d0);
    bft* kd = kb16 + ((size_t)(b * 4 + kv) * 2048 + tc * 64 + ti) * 64 + d0;
    #pragma unroll
    for (int i = 0; i < 4; ++i) {
        float4 a = ks[i];
        kd[i * 4 + 0] = __float2bfloat16(a.x); kd[i * 4 + 1] = __float2bfloat16(a.y);
        kd[i * 4 + 2] = __float2bfloat16(a.z); kd[i * 4 + 3] = __float2bfloat16(a.w);
        float4 c = vs[i];
        vt[ti * 65 + d0 + i * 4 + 0] = c.x; vt[ti * 65 + d0 + i * 4 + 1] = c.y;
        vt[ti * 65 + d0 + i * 4 + 2] = c.z; vt[ti * 65 + d0 + i * 4 + 3] = c.w;
    }
    __syncthreads();
    int d = t >> 2, ts0 = (t & 3) * 16;
    bft* vd = vT16 + ((size_t)(b * 4 + kv) * 64 + d) * 2048 + tc * 64 + ts0;
    #pragma unroll
    for (int i = 0; i < 16; ++i) vd[i] = __float2bfloat16(vt[(ts0 + i) * 65 + d]);
}

// ---------------- fused selected + window attention: KVBLK=32, swapped QK^T, packed P,
// ---------------- triple-buffered K/V, counted-vmcnt pipeline. 1024 blocks x 128 thr (head-pair split):
// ---------------- 4 independent 2-wave blocks/CU + balanced n-mix quadrant mapping ----------------
__global__ __launch_bounds__(128) void k_selwin(const bft* __restrict__ qb16, const bft* __restrict__ kb16,
                                                const bft* __restrict__ vT16, const int* __restrict__ sel,
                                                const float* __restrict__ gates, const bft* __restrict__ attb,
                                                bft* __restrict__ att16) {
    __shared__ __align__(16) bft Qs[64 * 64];
    __shared__ __align__(16) bft Ks[3][32 * 64];
    __shared__ __align__(16) bft Vs[3][64 * 32];
    __shared__ __align__(16) bft Ps[2][32 * 32];
    __shared__ int msL[40];
    __shared__ int nmS[2];
    // balanced bijective decode: quadrant q=(b,hp), group g=(kv,t); n = t or 63-t by quadrant
    int raw = blockIdx.x;
    int q_ = raw >> 8, g_ = raw & 255;
    int kv = g_ >> 6, t_ = g_ & 63;
    int n = ((q_ == 1) || (q_ == 2)) ? (63 - t_) : t_;
    int b = q_ >> 1, hp = q_ & 1;
    int bkv = b * 4 + kv;
    int tid = threadIdx.x;
    int w = tid >> 6, lane = tid & 63, lrow = lane & 15, lk = lane >> 4;
    int h = kv * 4 + hp * 2 + w;

    // stage Q: 64 rows (2 heads x 32 tokens) x 8 slots = 512 positions, 128 thr x 4 iters
    #pragma unroll
    for (int c = 0; c < 4; ++c) {
        int p = c * 128 + tid; int r = p >> 3, s = p & 7;
        const bft* src = qb16 + ((size_t)(b * cS + n * 32 + (r & 31))) * 1024 + (kv * 4 + hp * 2 + (r >> 5)) * 64 + ((s ^ (r & 7)) * 8);
        GL16(src, (char*)Qs + p * 16);
    }
    // stage K0/V0: 256 positions each, 128 thr x 2 iters
    #pragma unroll
    for (int it = 0; it < 2; ++it) {
        int p = it * 128 + tid;
        int row = p >> 3, s = p & 7;
        const bft* srck = kb16 + ((size_t)bkv * 2048 + n * 32 + row) * 64 + ((s ^ (row & 7)) * 8);
        GL16(srck, (char*)Ks[0] + p * 16);
        int rowv = p >> 2, g3 = p & 3;
        const bft* srcv = vT16 + ((size_t)bkv * 64 + rowv) * 2048 + n * 32 + ((g3 ^ (rowv & 3)) * 8);
        GL16(srcv, (char*)Vs[0] + p * 16);
    }
    if (tid == 0) {
        const int* selp = sel + ((size_t)bkv * cNB + n) * cTB;
        int nm = 0;
        #pragma unroll
        for (int t = 0; t < cTB; ++t) { int m = selp[t]; if (m <= n) msL[nm++] = m; }
        nmS[0] = nm;
        int m0 = (n > 16) ? (n - 16) : 0;
        for (int m = m0; m <= n; ++m) msL[nm++] = m;
        nmS[1] = nm;
    }
    // FULL drain (vmcnt AND lgkmcnt) before cross-wave read of msL/nmS.
    __syncthreads();

    int p1 = nmS[0], nm = nmS[1];
    bf16x8 qf[2][2];
    #pragma unroll
    for (int qt = 0; qt < 2; ++qt)
        #pragma unroll
        for (int kh = 0; kh < 2; ++kh) {
            int r = w * 32 + qt * 16 + lrow;
            qf[qt][kh] = *(const bf16x8*)((const char*)Qs + r * 128 + (((kh * 4 + lk) ^ (r & 7)) * 16));
        }

    f32x4 oa[2][4], accf[2][4];
    float sacc[2] = {0.f, 0.f};
    #pragma unroll
    for (int qt = 0; qt < 2; ++qt)
        #pragma unroll
        for (int dt = 0; dt < 4; ++dt) { oa[qt][dt] = (f32x4)0.f; accf[qt][dt] = (f32x4)0.f; }

    for (int i = 0; i < nm; ++i) {
        int buf = i % 3;
        if (i == 0 && nm > 1) {
            int m1 = msL[1];
            #pragma unroll
            for (int it = 0; it < 2; ++it) {
                int p = it * 128 + tid;
                int row = p >> 3, s = p & 7;
                const bft* srck = kb16 + ((size_t)bkv * 2048 + m1 * 32 + row) * 64 + ((s ^ (row & 7)) * 8);
                GL16(srck, (char*)Ks[1] + p * 16);
                int rowv = p >> 2, g3 = p & 3;
                const bft* srcv = vT16 + ((size_t)bkv * 64 + rowv) * 2048 + m1 * 32 + ((g3 ^ (rowv & 3)) * 8);
                GL16(srcv, (char*)Vs[1] + p * 16);
            }
        }
        if (i + 2 < nm) {
            int m2 = msL[i + 2]; int sl = (i + 2) % 3;
            #pragma unroll
            for (int it = 0; it < 2; ++it) {
                int p = it * 128 + tid;
                int row = p >> 3, s = p & 7;
                const bft* srck = kb16 + ((size_t)bkv * 2048 + m2 * 32 + row) * 64 + ((s ^ (row & 7)) * 8);
                GL16(srck, (char*)Ks[sl] + p * 16);
                int rowv = p >> 2, g3 = p & 3;
                const bft* srcv = vT16 + ((size_t)bkv * 64 + rowv) * 2048 + m2 * 32 + ((g3 ^ (rowv & 3)) * 8);
                GL16(srcv, (char*)Vs[sl] + p * 16);
            }
        }
        int m = msL[i];
        bool diag = (m == n);
        #pragma unroll
        for (int qt = 0; qt < 2; ++qt) {
            int q = qt * 16 + lrow;
            #pragma unroll
            for (int kt = 0; kt < 2; ++kt) {
                f32x4 a = (f32x4)0.f;
                #pragma unroll
                for (int kh = 0; kh < 2; ++kh) {
                    int kr = kt * 16 + lrow;
                    bf16x8 ak = *(const bf16x8*)((const char*)Ks[buf] + kr * 128 + (((kh * 4 + lk) ^ (kr & 7)) * 16));
                    a = __builtin_amdgcn_mfma_f32_16x16x32_bf16(ak, qf[qt][kh], a, 0, 0, 0);
                }
                int k0 = kt * 16 + lk * 4;
                float p0 = (!diag || k0 <= q)     ? __expf(a[0]) : 0.f;
                float p1v = (!diag || k0 + 1 <= q) ? __expf(a[1]) : 0.f;
                float p2 = (!diag || k0 + 2 <= q) ? __expf(a[2]) : 0.f;
                float p3 = (!diag || k0 + 3 <= q) ? __expf(a[3]) : 0.f;
                sacc[qt] += p0 + p1v + p2 + p3;
                bft h0 = __float2bfloat16(p0), h1 = __float2bfloat16(p1v);
                bft h2 = __float2bfloat16(p2), h3 = __float2bfloat16(p3);
                unsigned int w0 = ((unsigned int)(*(unsigned short*)&h1) << 16) | (unsigned int)(*(unsigned short*)&h0);
                unsigned int w1 = ((unsigned int)(*(unsigned short*)&h3) << 16) | (unsigned int)(*(unsigned short*)&h2);
                int g = kt * 2 + (lk >> 1);
                *(uint2*)((char*)Ps[w] + q * 64 + ((g ^ (q & 3)) * 16) + (lk & 1) * 8) = make_uint2(w0, w1);
            }
        }
        #pragma unroll
        for (int qt = 0; qt < 2; ++qt) {
            int q = qt * 16 + lrow;
            bf16x8 pa = *(const bf16x8*)((const char*)Ps[w] + q * 64 + ((lk ^ (q & 3)) * 16));
            #pragma unroll
            for (int dt = 0; dt < 4; ++dt) {
                int vr = dt * 16 + lrow;
                bf16x8 vb = *(const bf16x8*)((const char*)Vs[buf] + vr * 64 + ((lk ^ (vr & 3)) * 16));
                oa[qt][dt] = __builtin_amdgcn_mfma_f32_16x16x32_bf16(pa, vb, oa[qt][dt], 0, 0, 0);
            }
        }
        if (i == p1 - 1 || i == nm - 1) {
            int gi = (i == p1 - 1) ? 1 : 2;
            #pragma unroll
            for (int qt = 0; qt < 2; ++qt) {
                float s2 = sacc[qt];
                s2 += __shfl_xor(s2, 16); s2 += __shfl_xor(s2, 32);
                #pragma unroll
                for (int r = 0; r < 4; ++r) {
                    float l = __shfl(s2, lk * 4 + r);
                    int tok = n * 32 + qt * 16 + lk * 4 + r;
                    float g = gates[((size_t)(b * cS + tok)) * 48 + h * 3 + gi];
                    float f = g / l;
                    #pragma unroll
                    for (int dt = 0; dt < 4; ++dt) accf[qt][dt][r] += f * oa[qt][dt][r];
                }
                sacc[qt] = 0.f;
                #pragma unroll
                for (int dt = 0; dt < 4; ++dt) oa[qt][dt] = (f32x4)0.f;
            }
        }
        if (i + 1 < nm) {
            if (i + 2 < nm) { asm volatile("s_waitcnt vmcnt(4)" ::: "memory"); }
            else            { asm volatile("s_waitcnt vmcnt(0)" ::: "memory"); }
            FENCE; __builtin_amdgcn_s_barrier(); FENCE;
        }
    }
    #pragma unroll
    for (int qt = 0; qt < 2; ++qt)
        #pragma unroll
        for (int dt = 0; dt < 4; ++dt)
            #pragma unroll
            for (int r = 0; r < 4; ++r) {
                int tok = n * 32 + qt * 16 + lk * 4 + r;
                size_t a_ = ((size_t)(b * cS + tok)) * 1024 + h * 64 + dt * 16 + lrow;
                att16[a_] = __float2bfloat16(__bfloat162float(attb[a_]) + accf[qt][dt][r]);
            }
}

// ---------------- block means for importance ----------------
// 256 thr: 4 j-groups x 64 lanes, LDS tree-reduce (sync via __syncthreads only)
__global__ __launch_bounds__(256) void k_blockmeans(const float* __restrict__ k, const float* __restrict__ q,
                                                    float* __restrict__ kbm, float* __restrict__ qs) {
    __shared__ float redk[4][64], redq[4][64];
    int idx = blockIdx.x; int m = idx & 63; int kvb = idx >> 6; int kv = kvb & 3; int b = kvb >> 2;
    int jg = threadIdx.x >> 6, d = threadIdx.x & 63;
    float sk = 0.f, sq = 0.f;
    #pragma unroll
    for (int j = 0; j < 8; ++j) {
        int row = m * 32 + jg * 8 + j;
        sk += k[(size_t)(b * cS + row) * 256 + kv * 64 + d];
        size_t tb = (size_t)(b * cS + row) * 1024 + kv * 256 + d;
        sq += q[tb] + q[tb + 64] + q[tb + 128] + q[tb + 192];
    }
    redk[jg][d] = sk; redq[jg][d] = sq;
    __syncthreads();
    if (jg == 0) {
        size_t o = ((size_t)(b * cHKV + kv) * cNB + m) * 64 + d;
        kbm[o] = (redk[0][d] + redk[1][d] + redk[2][d] + redk[3][d]) * (1.f / 32.f);
        qs[o]  = (redq[0][d] + redq[1][d] + redq[2][d] + redq[3][d]) * (1.f / 32.f);
    }
}

// ---------------- importance + top-16 (jax.lax.top_k tie rule: lower index wins) ----------------
__global__ __launch_bounds__(64) void k_topk(const float* __restrict__ qs, const float* __restrict__ kbm,
                                             int* __restrict__ sel) {
    int idx = blockIdx.x; int n = idx & 63; int kvb = idx >> 6; int kv = kvb & 3; int b = kvb >> 2;
    int lane = threadIdx.x;
    __shared__ float qrow[64];
    size_t base = (size_t)(b * cHKV + kv) * cNB;
    qrow[lane] = qs[(base + n) * 64 + lane];
    __syncthreads();
    float val;
    if (lane <= n) {
        const float* kb = kbm + (base + lane) * 64;
        float s_ = 0.f;
        for (int d = 0; d < 64; ++d) s_ += qrow[d] * kb[d];
        val = (lane == n) ? 1e9f : s_;
    } else val = -1e9f;
    int* so = sel + (base + n) * cTB;
    float v_ = val;
    for (int t = 0; t < cTB; ++t) {
        float bv = v_; int bi = lane;
        #pragma unroll
        for (int o = 32; o; o >>= 1) {
            float ov = __shfl_xor(bv, o); int oi = __shfl_xor(bi, o);
            if (ov > bv || (ov == bv && oi < bi)) { bv = ov; bi = oi; }
        }
        if (lane == 0) so[t] = bi;
        if (lane == bi) v_ = -INFINITY;
    }
}

extern "C" void kernel_launch(void* const* d_in, const int* in_sizes, int n_in,
                              void* d_out, int out_size, void* d_ws, size_t ws_size,
                              hipStream_t stream) {
    const float* x    = (const float*)d_in[0];
    const float* ln1w = (const float*)d_in[1];
    const float* ln1b = (const float*)d_in[2];
    const float* wq   = (const float*)d_in[3];
    const float* bq   = (const float*)d_in[4];
    const float* wk   = (const float*)d_in[5];
    const float* bk   = (const float*)d_in[6];
    const float* wv   = (const float*)d_in[7];
    const float* bv   = (const float*)d_in[8];
    const float* wg   = (const float*)d_in[9];
    const float* bg   = (const float*)d_in[10];
    const float* wo   = (const float*)d_in[11];
    const float* bo   = (const float*)d_in[12];
    const float* ln2w = (const float*)d_in[13];
    const float* ln2b = (const float*)d_in[14];
    const float* w1   = (const float*)d_in[15];
    const float* b1   = (const float*)d_in[16];
    const float* w2   = (const float*)d_in[17];
    const float* b2   = (const float*)d_in[18];

    char* ws = (char*)d_ws;
    const size_t MiB = 1024 * 1024;
    bft*  wcatT = (bft*) (ws);                        // [1664][1024]
    bft*  woT   = (bft*) (ws + 3 * MiB + 256 * 1024); // [1024][1024]
    bft*  w1T   = (bft*) (ws + 5 * MiB + 256 * 1024); // [4096][1024]
    bft*  w2T   = (bft*) (ws + 13 * MiB + 256 * 1024);// [1024][4096]
    bft*  hbuf  = (bft*) (ws + 21 * MiB + 256 * 1024);// [4096][1024] bf16 (LN1/LN2 out; dead during attn)
    float* qbuf = (float*)(ws + 29 * MiB + 256 * 1024);// [4096][1024]
    float* kbuf = (float*)(ws + 45 * MiB + 256 * 1024);// [4096][256]
    float* vbuf = (float*)(ws + 49 * MiB + 256 * 1024);// [4096][256]
    float* gbuf = (float*)(ws + 53 * MiB + 256 * 1024);// [4096][48]
    bft*  ckb   = (bft*)  (ws + 55 * MiB + 256 * 1024);// [8][128][64] bf16
    bft*  cvTb  = (bft*)  (ws + 56 * MiB + 256 * 1024);// [8][64][128] bf16
    float* kbmb = (float*)(ws + 57 * MiB + 256 * 1024);
    float* qsb  = (float*)(ws + 57 * MiB + 384 * 1024);
    int*   selb = (int*)  (ws + 57 * MiB + 512 * 1024);
    bft*  attb16= (bft*) (ws + 58 * MiB);             // [4096][1024] bf16 (g0*oc)
    bft*  att16 = (bft*) (ws + 74 * MiB);             // [4096][1024] bf16
    float* x1b  = (float*)(ws + 82 * MiB);            // [4096][1024] f32
    bft*  zbuf  = (bft*) (ws + 29 * MiB + 256 * 1024);// [4096][4096] bf16, aliases dead qkv region
    bft*  kb16  = (bft*) (ws + 21 * MiB + 256 * 1024);// [8][2048][64] bf16, 2 MiB
    bft*  vT16  = (bft*) (ws + 23 * MiB + 256 * 1024);// [8][64][2048] bf16, 2 MiB
    bft*  qb16  = (bft*) (ws + 82 * MiB);             // [4096][1024] bf16 prescaled, aliases x1b (dead until wo-GEMM)
    // split-K partials for MLP-down: 4 x 8 MiB bf16, placed in regions dead at MLP-down time
    bft*  skp0  = (bft*) (ws);                         // over wcatT/woT/w1T head (dead)
    bft*  skp1  = (bft*) (ws + 21 * MiB + 256 * 1024); // over hbuf (dead after MLP-up)
    bft*  skp2  = (bft*) (ws + 61 * MiB + 256 * 1024); // over attb tail (dead)
    bft*  skp3  = (bft*) (ws + 69 * MiB + 256 * 1024); // over attb/att16 tail (dead)

    dim3 t328(32, 8);
    // fused QKVG weight transpose (replaces 4 launches + memset)
    k_transpose_qkvg<<<dim3(32, 52), t328, 0, stream>>>(wq, wk, wv, wg, wcatT);
    k_transpose_cvt<<<dim3(32, 32), t328, 0, stream>>>(wo, woT, 1024, 1024);
    k_transpose_cvt<<<dim3(32, 128), t328, 0, stream>>>(w1, w1T, 1024, 4096);
    k_transpose_cvt<<<dim3(128, 32), t328, 0, stream>>>(w2, w2T, 4096, 1024);
    k_ln<<<4096, 256, 0, stream>>>(x, ln1w, ln1b, hbuf);
    k_gemm<0><<<dim3(13, 32), 256, 0, stream>>>(hbuf, wcatT, 4096, 1664, 1024,
        nullptr, nullptr, nullptr, nullptr, qbuf, kbuf, vbuf, gbuf, bq, bk, bv, bg, qb16);
    k_kvprep<<<256, 256, 0, stream>>>(kbuf, vbuf, kb16, vT16);
    k_cmp_kv<<<8 * 128, 256, 0, stream>>>(kbuf, vbuf, ckb, cvTb);
    k_cmp_attn<<<256, 256, 0, stream>>>(qb16, ckb, cvTb, gbuf, attb16);
    k_blockmeans<<<cB * cHKV * cNB, 256, 0, stream>>>(kbuf, qbuf, kbmb, qsb);
    k_topk<<<cB * cHKV * cNB, 64, 0, stream>>>(qsb, kbmb, selb);
    k_selwin<<<1024, 128, 0, stream>>>(qb16, kb16, vT16, selb, gbuf, attb16, att16);
    k_gemm<1><<<dim3(8, 32), 256, 0, stream>>>(att16, woT, 4096, 1024, 1024,
        bo, x, x1b, nullptr, nullptr, nullptr, nullptr, nullptr, nullptr, nullptr, nullptr, nullptr, nullptr);
    k_ln<<<4096, 256, 0, stream>>>(x1b, ln2w, ln2b, hbuf);
    // MLP up + GELU: 256^2 8-phase kernel
    k_gemm256_gelu<<<dim3(16, 16), 512, 0, stream>>>(hbuf, w1T, b1, zbuf);
    // MLP down: split-K x4 256^2 8-phase + fused reduce (bias + residual)
    k_gemm256_sk<<<256, 512, 0, stream>>>(zbuf, w2T, skp0, skp1, skp2, skp3);
    k_mlpred<<<2048, 256, 0, stream>>>(skp0, skp1, skp2, skp3, x1b, b2, (float*)d_out);
}

// Round 19
// 264.729 us; speedup vs baseline: 1.0454x; 1.0454x over previous
//
#include <hip/hip_runtime.h>
#include <hip/hip_bf16.h>
#include <math.h>

typedef __hip_bfloat16 bft;
typedef __attribute__((ext_vector_type(8))) short bf16x8;
typedef __attribute__((ext_vector_type(4))) float f32x4;

constexpr int cB = 2, cS = 2048, cD = 1024, cH = 16, cHKV = 4, cGQ = 4, cHD = 64;
constexpr int cBS = 32, cTB = 16, cNB = 64, cNC = 127;

#define GL16(gp, lp) __builtin_amdgcn_global_load_lds((const __attribute__((address_space(1))) void*)(gp), (__attribute__((address_space(3))) void*)(lp), 16, 0, 0)
#define FENCE asm volatile("" ::: "memory")

__device__ __forceinline__ float bf2f(short h) {
    return __uint_as_float(((unsigned int)(unsigned short)h) << 16);
}

// ---------------- fused QKVG weight transpose: wcat[1664][1024] from wq/wk/wv/wg (+zero pad) ----------------
__global__ void k_transpose_qkvg(const float* __restrict__ wq, const float* __restrict__ wk,
                                 const float* __restrict__ wv, const float* __restrict__ wg,
                                 bft* __restrict__ dst) {
    __shared__ float tile[32][33];
    int kb = blockIdx.x * 32, nb = blockIdx.y * 32;   // nb in [0,1664)
    const float* src; int N, off;
    if (nb < 1024)      { src = wq; N = 1024; off = 0; }
    else if (nb < 1280) { src = wk; N = 256;  off = 1024; }
    else if (nb < 1536) { src = wv; N = 256;  off = 1280; }
    else                { src = wg; N = 48;   off = 1536; }
    int tx = threadIdx.x, ty = threadIdx.y; // 32 x 8
    #pragma unroll
    for (int i = 0; i < 32; i += 8) {
        int k = kb + ty + i, n = nb - off + tx;
        tile[ty + i][tx] = (n < N) ? src[(size_t)k * N + n] : 0.f;
    }
    __syncthreads();
    #pragma unroll
    for (int i = 0; i < 32; i += 8) {
        int n = nb + ty + i, k = kb + tx;
        dst[(size_t)n * 1024 + k] = __float2bfloat16(tile[tx][ty + i]);
    }
}

// ---------------- fused wo/w1/w2 transpose (3 launches -> 1): flat grid 9216 ----------------
__global__ void k_transpose_w3(const float* __restrict__ wo, const float* __restrict__ w1,
                               const float* __restrict__ w2,
                               bft* __restrict__ woT, bft* __restrict__ w1T, bft* __restrict__ w2T) {
    __shared__ float tile[32][33];
    int idx = blockIdx.x;
    const float* src; bft* dst; int K, N, kb, nb;
    if (idx < 1024)      { src = wo; dst = woT; K = 1024; N = 1024; kb = (idx & 31) * 32;  nb = (idx >> 5) * 32; }
    else if (idx < 5120) { int r = idx - 1024; src = w1; dst = w1T; K = 1024; N = 4096; kb = (r & 31) * 32;  nb = (r >> 5) * 32; }
    else                 { int r = idx - 5120; src = w2; dst = w2T; K = 4096; N = 1024; kb = (r & 127) * 32; nb = (r >> 7) * 32; }
    int tx = threadIdx.x, ty = threadIdx.y; // 32 x 8
    #pragma unroll
    for (int i = 0; i < 32; i += 8) {
        int k = kb + ty + i, n = nb + tx;
        tile[ty + i][tx] = src[(size_t)k * N + n];
    }
    __syncthreads();
    #pragma unroll
    for (int i = 0; i < 32; i += 8) {
        int n = nb + ty + i, k = kb + tx;
        dst[(size_t)n * K + k] = __float2bfloat16(tile[tx][ty + i]);
    }
}

// ---------------- LayerNorm (fp32 in, bf16 out) ----------------
__global__ __launch_bounds__(256) void k_ln(const float* __restrict__ src, const float* __restrict__ w,
                                            const float* __restrict__ b, bft* __restrict__ dst) {
    int row = blockIdx.x; int t = threadIdx.x;
    const float4* xr = (const float4*)(src + (size_t)row * cD);
    float4 v = xr[t];
    float s = v.x + v.y + v.z + v.w;
    #pragma unroll
    for (int o = 32; o; o >>= 1) s += __shfl_xor(s, o);
    __shared__ float red[8];
    int wid = t >> 6, lane = t & 63;
    if (lane == 0) red[wid] = s;
    __syncthreads();
    float mean = (red[0] + red[1] + red[2] + red[3]) * (1.f / cD);
    float dx = v.x - mean, dy = v.y - mean, dz = v.z - mean, dw = v.w - mean;
    float sq = dx * dx + dy * dy + dz * dz + dw * dw;
    #pragma unroll
    for (int o = 32; o; o >>= 1) sq += __shfl_xor(sq, o);
    if (lane == 0) red[4 + wid] = sq;
    __syncthreads();
    float var = (red[4] + red[5] + red[6] + red[7]) * (1.f / cD);
    float rstd = rsqrtf(var + 1e-5f);
    float4 wv = ((const float4*)w)[t];
    float4 bv = ((const float4*)b)[t];
    bft* o_ = dst + (size_t)row * cD + t * 4;
    o_[0] = __float2bfloat16(dx * rstd * wv.x + bv.x);
    o_[1] = __float2bfloat16(dy * rstd * wv.y + bv.y);
    o_[2] = __float2bfloat16(dz * rstd * wv.z + bv.z);
    o_[3] = __float2bfloat16(dw * rstd * wv.w + bv.w);
}

// ---------------- MFMA GEMM 128^2 (m97 structure + XCD swizzle): C = A * Bt^T ----------------
template<int MODE>
__global__ __launch_bounds__(256) void k_gemm(const bft* __restrict__ A, const bft* __restrict__ Bt,
        int M, int N, int K,
        const float* __restrict__ bias, const float* __restrict__ add,
        float* __restrict__ outf, bft* __restrict__ outb,
        float* __restrict__ oq, float* __restrict__ okk, float* __restrict__ ovv, float* __restrict__ og,
        const float* __restrict__ bq, const float* __restrict__ bk,
        const float* __restrict__ bv, const float* __restrict__ bg,
        bft* __restrict__ oqb) {
    __shared__ __align__(16) bft As[128 * 64];
    __shared__ __align__(16) bft Bs[128 * 64];
    int tid = threadIdx.x;
    int nwg = gridDim.x * gridDim.y;
    int bid = blockIdx.y * gridDim.x + blockIdx.x;
    int q8 = nwg >> 3;
    int wg = (bid & 7) * q8 + (bid >> 3);
    int bx = wg % gridDim.x, by = wg / gridDim.x;
    int m0 = by * 128, n0 = bx * 128;
    int lane = tid & 63, wid = tid >> 6;
    int wr = wid >> 1, wc = wid & 1;
    int lrow = lane & 15, lk = lane >> 4;
    f32x4 acc[4][4];
    #pragma unroll
    for (int i = 0; i < 4; ++i)
        #pragma unroll
        for (int j = 0; j < 4; ++j) acc[i][j] = (f32x4)0.f;

    for (int kt = 0; kt < K; kt += 64) {
        #pragma unroll
        for (int sh = 0; sh < 4; ++sh) {
            int p = sh * 256 + tid;
            int row = p >> 3;
            int slot = p & 7;
            int ss = slot ^ (row & 7);
            const bft* ga = A + (size_t)(m0 + row) * K + kt + ss * 8;
            const bft* gb = Bt + (size_t)(n0 + row) * K + kt + ss * 8;
            GL16(ga, (char*)As + p * 16);
            GL16(gb, (char*)Bs + p * 16);
        }
        __syncthreads();
        #pragma unroll
        for (int kh = 0; kh < 2; ++kh) {
            bf16x8 af[4], bfv[4];
            #pragma unroll
            for (int mi = 0; mi < 4; ++mi) {
                int row = wr * 64 + mi * 16 + lrow;
                int c8 = kh * 4 + lk;
                af[mi] = *(const bf16x8*)((const char*)As + row * 128 + ((c8 ^ (row & 7)) * 16));
            }
            #pragma unroll
            for (int ni = 0; ni < 4; ++ni) {
                int row = wc * 64 + ni * 16 + lrow;
                int c8 = kh * 4 + lk;
                bfv[ni] = *(const bf16x8*)((const char*)Bs + row * 128 + ((c8 ^ (row & 7)) * 16));
            }
            #pragma unroll
            for (int mi = 0; mi < 4; ++mi)
                #pragma unroll
                for (int ni = 0; ni < 4; ++ni)
                    acc[mi][ni] = __builtin_amdgcn_mfma_f32_16x16x32_bf16(af[mi], bfv[ni], acc[mi][ni], 0, 0, 0);
        }
        __syncthreads();
    }
    #pragma unroll
    for (int mi = 0; mi < 4; ++mi)
        #pragma unroll
        for (int ni = 0; ni < 4; ++ni)
            #pragma unroll
            for (int r = 0; r < 4; ++r) {
                int gr = m0 + wr * 64 + mi * 16 + lk * 4 + r;
                int gc = n0 + wc * 64 + ni * 16 + lrow;
                float val = acc[mi][ni][r];
                if (MODE == 0) {
                    if (gc < 1024) {
                        float qv2 = val + bq[gc];
                        oq[(size_t)gr * 1024 + gc] = qv2;
                        oqb[(size_t)gr * 1024 + gc] = __float2bfloat16(qv2 * 0.125f);
                    }
                    else if (gc < 1280) okk[(size_t)gr * 256 + gc - 1024] = val + bk[gc - 1024];
                    else if (gc < 1536) ovv[(size_t)gr * 256 + gc - 1280] = val + bv[gc - 1280];
                    else if (gc < 1584) {
                        float t2 = val + bg[gc - 1536];
                        og[(size_t)gr * 48 + gc - 1536] = 1.f / (1.f + __expf(-t2));
                    }
                } else if (MODE == 1) {
                    size_t o = (size_t)gr * N + gc;
                    outf[o] = val + bias[gc] + add[o];
                } else if (MODE == 2) {
                    float t2 = val + bias[gc];
                    float ge = 0.5f * t2 * (1.f + erff(t2 * 0.70710678118654752f));
                    outb[(size_t)gr * N + gc] = __float2bfloat16(ge);
                } else {
                    size_t o = (size_t)gr * N + gc;
                    outf[o] = val + bias[gc] + add[o];
                }
            }
}

// ---------------- 256^2 8-phase GEMM (T2+T3+T4+T5), fused GELU: zbuf = gelu(hbuf @ w1T^T + b1) ----------------
__global__ __launch_bounds__(512) void k_gemm256_gelu(const bft* __restrict__ A, const bft* __restrict__ Bt,
                                                      const float* __restrict__ bias, bft* __restrict__ outb) {
    constexpr int K = 1024, N = 4096, NT = K / 64;
    __shared__ __align__(16) bft As[2][256 * 64];
    __shared__ __align__(16) bft Bs[2][256 * 64];
    int tid = threadIdx.x;
    int nwg = gridDim.x * gridDim.y;                 // 256
    int bid = blockIdx.y * gridDim.x + blockIdx.x;
    int q8 = nwg >> 3;
    int wg = (bid & 7) * q8 + (bid >> 3);            // bijective XCD swizzle
    int bx = wg % gridDim.x, by = wg / gridDim.x;
    int m0 = by * 256, n0 = bx * 256;
    int w = tid >> 6, lane = tid & 63, lrow = lane & 15, lk = lane >> 4;
    int wr = w >> 2, wc = w & 3;
    int l8 = lane >> 3, l7 = lane & 7;
    int ssrc = (l7 ^ l8) * 8;

    auto stageA = [&](int buf, int h, int kt) {
        int rbase = 32 * w + 16 * h;
        const bft* g0 = A + (size_t)(m0 + rbase + l8) * K + kt + ssrc;
        GL16(g0, (char*)As[buf] + rbase * 128 + lane * 16);
        const bft* g1 = A + (size_t)(m0 + rbase + 8 + l8) * K + kt + ssrc;
        GL16(g1, (char*)As[buf] + rbase * 128 + 1024 + lane * 16);
    };
    auto stageB = [&](int buf, int h, int kt) {
        int rbase = 32 * w + 16 * h;
        const bft* g0 = Bt + (size_t)(n0 + rbase + l8) * K + kt + ssrc;
        GL16(g0, (char*)Bs[buf] + rbase * 128 + lane * 16);
        const bft* g1 = Bt + (size_t)(n0 + rbase + 8 + l8) * K + kt + ssrc;
        GL16(g1, (char*)Bs[buf] + rbase * 128 + 1024 + lane * 16);
    };
    auto ldA = [&](int buf, int mi, int kk) {
        int r = wr * 128 + mi * 16 + lrow;
        return *(const bf16x8*)((const char*)As[buf] + r * 128 + (((kk * 4 + lk) ^ (r & 7)) * 16));
    };
    auto ldB = [&](int buf, int ni, int kk) {
        int r = wc * 64 + ni * 16 + lrow;
        return *(const bf16x8*)((const char*)Bs[buf] + r * 128 + (((kk * 4 + lk) ^ (r & 7)) * 16));
    };

    f32x4 acc[8][4];
    #pragma unroll
    for (int i = 0; i < 8; ++i)
        #pragma unroll
        for (int j = 0; j < 4; ++j) acc[i][j] = (f32x4)0.f;

    stageA(0, 0, 0); stageB(0, 0, 0); stageA(0, 1, 0); stageB(0, 1, 0);
    asm volatile("s_waitcnt vmcnt(4)" ::: "memory");
    FENCE; __builtin_amdgcn_s_barrier(); FENCE;

    bf16x8 aE[4][2], aO[4][2], bE[2][2], bO[2][2];
    for (int t = 0; t < NT; ++t) {
        int cur = t & 1, nxt = cur ^ 1;
        int ktn = (t + 1) * 64;
        bool pre = (t + 1 < NT);
        #pragma unroll
        for (int i = 0; i < 4; ++i)
            #pragma unroll
            for (int kk = 0; kk < 2; ++kk) aE[i][kk] = ldA(cur, 2 * i, kk);
        #pragma unroll
        for (int j = 0; j < 2; ++j)
            #pragma unroll
            for (int kk = 0; kk < 2; ++kk) bE[j][kk] = ldB(cur, 2 * j, kk);
        if (pre) { stageA(nxt, 0, ktn); asm volatile("s_waitcnt vmcnt(2)" ::: "memory"); }
        else     {                       asm volatile("s_waitcnt vmcnt(0)" ::: "memory"); }
        FENCE; __builtin_amdgcn_s_barrier(); FENCE;
        __builtin_amdgcn_s_setprio(1);
        #pragma unroll
        for (int i = 0; i < 4; ++i)
            #pragma unroll
            for (int j = 0; j < 2; ++j)
                #pragma unroll
                for (int kk = 0; kk < 2; ++kk)
                    acc[2 * i][2 * j] = __builtin_amdgcn_mfma_f32_16x16x32_bf16(aE[i][kk], bE[j][kk], acc[2 * i][2 * j], 0, 0, 0);
        __builtin_amdgcn_s_setprio(0);
        FENCE; __builtin_amdgcn_s_barrier(); FENCE;
        #pragma unroll
        for (int j = 0; j < 2; ++j)
            #pragma unroll
            for (int kk = 0; kk < 2; ++kk) bO[j][kk] = ldB(cur, 2 * j + 1, kk);
        if (pre) stageB(nxt, 0, ktn);
        FENCE; __builtin_amdgcn_s_barrier(); FENCE;
        __builtin_amdgcn_s_setprio(1);
        #pragma unroll
        for (int i = 0; i < 4; ++i)
            #pragma unroll
            for (int j = 0; j < 2; ++j)
                #pragma unroll
                for (int kk = 0; kk < 2; ++kk)
                    acc[2 * i][2 * j + 1] = __builtin_amdgcn_mfma_f32_16x16x32_bf16(aE[i][kk], bO[j][kk], acc[2 * i][2 * j + 1], 0, 0, 0);
        __builtin_amdgcn_s_setprio(0);
        FENCE; __builtin_amdgcn_s_barrier(); FENCE;
        #pragma unroll
        for (int i = 0; i < 4; ++i)
            #pragma unroll
            for (int kk = 0; kk < 2; ++kk) aO[i][kk] = ldA(cur, 2 * i + 1, kk);
        if (pre) stageA(nxt, 1, ktn);
        FENCE; __builtin_amdgcn_s_barrier(); FENCE;
        __builtin_amdgcn_s_setprio(1);
        #pragma unroll
        for (int i = 0; i < 4; ++i)
            #pragma unroll
            for (int j = 0; j < 2; ++j)
                #pragma unroll
                for (int kk = 0; kk < 2; ++kk)
                    acc[2 * i + 1][2 * j] = __builtin_amdgcn_mfma_f32_16x16x32_bf16(aO[i][kk], bE[j][kk], acc[2 * i + 1][2 * j], 0, 0, 0);
        __builtin_amdgcn_s_setprio(0);
        FENCE; __builtin_amdgcn_s_barrier(); FENCE;
        if (pre) { stageB(nxt, 1, ktn); asm volatile("s_waitcnt vmcnt(4)" ::: "memory"); }
        FENCE; __builtin_amdgcn_s_barrier(); FENCE;
        __builtin_amdgcn_s_setprio(1);
        #pragma unroll
        for (int i = 0; i < 4; ++i)
            #pragma unroll
            for (int j = 0; j < 2; ++j)
                #pragma unroll
                for (int kk = 0; kk < 2; ++kk)
                    acc[2 * i + 1][2 * j + 1] = __builtin_amdgcn_mfma_f32_16x16x32_bf16(aO[i][kk], bO[j][kk], acc[2 * i + 1][2 * j + 1], 0, 0, 0);
        __builtin_amdgcn_s_setprio(0);
        FENCE; __builtin_amdgcn_s_barrier(); FENCE;
    }
    #pragma unroll
    for (int mi = 0; mi < 8; ++mi)
        #pragma unroll
        for (int ni = 0; ni < 4; ++ni)
            #pragma unroll
            for (int r = 0; r < 4; ++r) {
                int gr = m0 + wr * 128 + mi * 16 + lk * 4 + r;
                int gc = n0 + wc * 64 + ni * 16 + lrow;
                float t2 = acc[mi][ni][r] + bias[gc];
                float ge = 0.5f * t2 * (1.f + erff(t2 * 0.70710678118654752f));
                outb[(size_t)gr * N + gc] = __float2bfloat16(ge);
            }
}

// ---------------- 256^2 8-phase split-K GEMM for MLP-down: partials = zbuf @ w2T^T (bf16) ----------------
__global__ __launch_bounds__(512) void k_gemm256_sk(const bft* __restrict__ A, const bft* __restrict__ Bt,
                                                    bft* __restrict__ q0, bft* __restrict__ q1,
                                                    bft* __restrict__ q2, bft* __restrict__ q3) {
    constexpr int KT = 4096, N = 1024, NT = 16;
    __shared__ __align__(16) bft As[2][256 * 64];
    __shared__ __align__(16) bft Bs[2][256 * 64];
    int tid = threadIdx.x;
    int flat = blockIdx.x;
    int wg = (flat & 7) * 32 + (flat >> 3);          // bijective XCD swizzle over 256
    int slice = wg >> 6; int rem = wg & 63;
    int m0 = (rem >> 2) * 256, n0 = (rem & 3) * 256;
    int kbase = slice * 1024;
    int w = tid >> 6, lane = tid & 63, lrow = lane & 15, lk = lane >> 4;
    int wr = w >> 2, wc = w & 3;
    int l8 = lane >> 3, l7 = lane & 7;
    int ssrc = (l7 ^ l8) * 8;

    auto stageA = [&](int buf, int h, int kt) {
        int rbase = 32 * w + 16 * h;
        const bft* g0 = A + (size_t)(m0 + rbase + l8) * KT + kbase + kt + ssrc;
        GL16(g0, (char*)As[buf] + rbase * 128 + lane * 16);
        const bft* g1 = A + (size_t)(m0 + rbase + 8 + l8) * KT + kbase + kt + ssrc;
        GL16(g1, (char*)As[buf] + rbase * 128 + 1024 + lane * 16);
    };
    auto stageB = [&](int buf, int h, int kt) {
        int rbase = 32 * w + 16 * h;
        const bft* g0 = Bt + (size_t)(n0 + rbase + l8) * KT + kbase + kt + ssrc;
        GL16(g0, (char*)Bs[buf] + rbase * 128 + lane * 16);
        const bft* g1 = Bt + (size_t)(n0 + rbase + 8 + l8) * KT + kbase + kt + ssrc;
        GL16(g1, (char*)Bs[buf] + rbase * 128 + 1024 + lane * 16);
    };
    auto ldA = [&](int buf, int mi, int kk) {
        int r = wr * 128 + mi * 16 + lrow;
        return *(const bf16x8*)((const char*)As[buf] + r * 128 + (((kk * 4 + lk) ^ (r & 7)) * 16));
    };
    auto ldB = [&](int buf, int ni, int kk) {
        int r = wc * 64 + ni * 16 + lrow;
        return *(const bf16x8*)((const char*)Bs[buf] + r * 128 + (((kk * 4 + lk) ^ (r & 7)) * 16));
    };

    f32x4 acc[8][4];
    #pragma unroll
    for (int i = 0; i < 8; ++i)
        #pragma unroll
        for (int j = 0; j < 4; ++j) acc[i][j] = (f32x4)0.f;

    stageA(0, 0, 0); stageB(0, 0, 0); stageA(0, 1, 0); stageB(0, 1, 0);
    asm volatile("s_waitcnt vmcnt(4)" ::: "memory");
    FENCE; __builtin_amdgcn_s_barrier(); FENCE;

    bf16x8 aE[4][2], aO[4][2], bE[2][2], bO[2][2];
    for (int t = 0; t < NT; ++t) {
        int cur = t & 1, nxt = cur ^ 1;
        int ktn = (t + 1) * 64;
        bool pre = (t + 1 < NT);
        #pragma unroll
        for (int i = 0; i < 4; ++i)
            #pragma unroll
            for (int kk = 0; kk < 2; ++kk) aE[i][kk] = ldA(cur, 2 * i, kk);
        #pragma unroll
        for (int j = 0; j < 2; ++j)
            #pragma unroll
            for (int kk = 0; kk < 2; ++kk) bE[j][kk] = ldB(cur, 2 * j, kk);
        if (pre) { stageA(nxt, 0, ktn); asm volatile("s_waitcnt vmcnt(2)" ::: "memory"); }
        else     {                       asm volatile("s_waitcnt vmcnt(0)" ::: "memory"); }
        FENCE; __builtin_amdgcn_s_barrier(); FENCE;
        __builtin_amdgcn_s_setprio(1);
        #pragma unroll
        for (int i = 0; i < 4; ++i)
            #pragma unroll
            for (int j = 0; j < 2; ++j)
                #pragma unroll
                for (int kk = 0; kk < 2; ++kk)
                    acc[2 * i][2 * j] = __builtin_amdgcn_mfma_f32_16x16x32_bf16(aE[i][kk], bE[j][kk], acc[2 * i][2 * j], 0, 0, 0);
        __builtin_amdgcn_s_setprio(0);
        FENCE; __builtin_amdgcn_s_barrier(); FENCE;
        #pragma unroll
        for (int j = 0; j < 2; ++j)
            #pragma unroll
            for (int kk = 0; kk < 2; ++kk) bO[j][kk] = ldB(cur, 2 * j + 1, kk);
        if (pre) stageB(nxt, 0, ktn);
        FENCE; __builtin_amdgcn_s_barrier(); FENCE;
        __builtin_amdgcn_s_setprio(1);
        #pragma unroll
        for (int i = 0; i < 4; ++i)
            #pragma unroll
            for (int j = 0; j < 2; ++j)
                #pragma unroll
                for (int kk = 0; kk < 2; ++kk)
                    acc[2 * i][2 * j + 1] = __builtin_amdgcn_mfma_f32_16x16x32_bf16(aE[i][kk], bO[j][kk], acc[2 * i][2 * j + 1], 0, 0, 0);
        __builtin_amdgcn_s_setprio(0);
        FENCE; __builtin_amdgcn_s_barrier(); FENCE;
        #pragma unroll
        for (int i = 0; i < 4; ++i)
            #pragma unroll
            for (int kk = 0; kk < 2; ++kk) aO[i][kk] = ldA(cur, 2 * i + 1, kk);
        if (pre) stageA(nxt, 1, ktn);
        FENCE; __builtin_amdgcn_s_barrier(); FENCE;
        __builtin_amdgcn_s_setprio(1);
        #pragma unroll
        for (int i = 0; i < 4; ++i)
            #pragma unroll
            for (int j = 0; j < 2; ++j)
                #pragma unroll
                for (int kk = 0; kk < 2; ++kk)
                    acc[2 * i + 1][2 * j] = __builtin_amdgcn_mfma_f32_16x16x32_bf16(aO[i][kk], bE[j][kk], acc[2 * i + 1][2 * j], 0, 0, 0);
        __builtin_amdgcn_s_setprio(0);
        FENCE; __builtin_amdgcn_s_barrier(); FENCE;
        if (pre) { stageB(nxt, 1, ktn); asm volatile("s_waitcnt vmcnt(4)" ::: "memory"); }
        FENCE; __builtin_amdgcn_s_barrier(); FENCE;
        __builtin_amdgcn_s_setprio(1);
        #pragma unroll
        for (int i = 0; i < 4; ++i)
            #pragma unroll
            for (int j = 0; j < 2; ++j)
                #pragma unroll
                for (int kk = 0; kk < 2; ++kk)
                    acc[2 * i + 1][2 * j + 1] = __builtin_amdgcn_mfma_f32_16x16x32_bf16(aO[i][kk], bO[j][kk], acc[2 * i + 1][2 * j + 1], 0, 0, 0);
        __builtin_amdgcn_s_setprio(0);
        FENCE; __builtin_amdgcn_s_barrier(); FENCE;
    }
    bft* pp = (slice == 0) ? q0 : (slice == 1) ? q1 : (slice == 2) ? q2 : q3;
    #pragma unroll
    for (int mi = 0; mi < 8; ++mi)
        #pragma unroll
        for (int ni = 0; ni < 4; ++ni)
            #pragma unroll
            for (int r = 0; r < 4; ++r) {
                int gr = m0 + wr * 128 + mi * 16 + lk * 4 + r;
                int gc = n0 + wc * 64 + ni * 16 + lrow;
                pp[(size_t)gr * N + gc] = __float2bfloat16(acc[mi][ni][r]);
            }
}

// ---------------- split-K reduce: out = x1 + b2 + sum(partials) ----------------
__global__ __launch_bounds__(256) void k_mlpred(const bft* __restrict__ q0, const bft* __restrict__ q1,
                                                const bft* __restrict__ q2, const bft* __restrict__ q3,
                                                const float* __restrict__ x1, const float* __restrict__ b2,
                                                float* __restrict__ out) {
    size_t i = ((size_t)blockIdx.x * 256 + threadIdx.x) * 8;
    bf16x8 a0 = *(const bf16x8*)(q0 + i);
    bf16x8 a1 = *(const bf16x8*)(q1 + i);
    bf16x8 a2 = *(const bf16x8*)(q2 + i);
    bf16x8 a3 = *(const bf16x8*)(q3 + i);
    int col = (int)(i & 1023);
    float4 b0 = *(const float4*)(b2 + col);
    float4 b1v = *(const float4*)(b2 + col + 4);
    float4 x0 = *(const float4*)(x1 + i);
    float4 x1v = *(const float4*)(x1 + i + 4);
    float s[8];
    #pragma unroll
    for (int j = 0; j < 8; ++j)
        s[j] = bf2f(a0[j]) + bf2f(a1[j]) + bf2f(a2[j]) + bf2f(a3[j]);
    float4 o0 = make_float4(s[0] + b0.x + x0.x, s[1] + b0.y + x0.y, s[2] + b0.z + x0.z, s[3] + b0.w + x0.w);
    float4 o1 = make_float4(s[4] + b1v.x + x1v.x, s[5] + b1v.y + x1v.y, s[6] + b1v.z + x1v.z, s[7] + b1v.w + x1v.w);
    *(float4*)(out + i) = o0;
    *(float4*)(out + i + 4) = o1;
}

// ---------------- fused KV utilities (3 launches -> 1): kvprep | cmp_kv | blockmeans ----------------
// blocks [0,256): kvprep; [256,1280): cmp_kv; [1280,1792): blockmeans. All 256 thr, block-uniform barriers.
__global__ __launch_bounds__(256) void k_kvutil(const float* __restrict__ k, const float* __restrict__ v,
                                                const float* __restrict__ q,
                                                bft* __restrict__ kb16, bft* __restrict__ vT16,
                                                bft* __restrict__ ck, bft* __restrict__ cvT,
                                                float* __restrict__ kbm, float* __restrict__ qs) {
    __shared__ float vt[64 * 65];
    __shared__ float redk[4][64], redv[4][64];
    int idx = blockIdx.x;
    int t = threadIdx.x;
    if (idx < 256) {
        // ---- kvprep: K/V -> bf16 (+V transpose) ----
        int tc = idx & 31; int kv = (idx >> 5) & 3; int b = idx >> 7;
        int ti = t >> 2, seg = t & 3, d0 = seg * 16;
        const float4* ks = (const float4*)(k + (size_t)(b * cS + tc * 64 + ti) * 256 + kv * 64 + d0);
        const float4* vs = (const float4*)(v + (size_t)(b * cS + tc * 64 + ti) * 256 + kv * 64 + d0);
        bft* kd = kb16 + ((size_t)(b * 4 + kv) * 2048 + tc * 64 + ti) * 64 + d0;
        #pragma unroll
        for (int i = 0; i < 4; ++i) {
            float4 a = ks[i];
            kd[i * 4 + 0] = __float2bfloat16(a.x); kd[i * 4 + 1] = __float2bfloat16(a.y);
            kd[i * 4 + 2] = __float2bfloat16(a.z); kd[i * 4 + 3] = __float2bfloat16(a.w);
            float4 c = vs[i];
            vt[ti * 65 + d0 + i * 4 + 0] = c.x; vt[ti * 65 + d0 + i * 4 + 1] = c.y;
            vt[ti * 65 + d0 + i * 4 + 2] = c.z; vt[ti * 65 + d0 + i * 4 + 3] = c.w;
        }
        __syncthreads();
        int d = t >> 2, ts0 = (t & 3) * 16;
        bft* vd = vT16 + ((size_t)(b * 4 + kv) * 64 + d) * 2048 + tc * 64 + ts0;
        #pragma unroll
        for (int i = 0; i < 16; ++i) vd[i] = __float2bfloat16(vt[(ts0 + i) * 65 + d]);
    } else if (idx < 1280) {
        // ---- cmp_kv: compressed K/V means -> bf16 ----
        int i2 = idx - 256;
        int n = i2 & 127; int bk = i2 >> 7; int kv = bk & 3; int b = bk >> 2;
        int jg = t >> 6, d = t & 63;
        if (n == 127) {
            if (t < 64) {
                ck[(size_t)bk * 8192 + 127 * 64 + d] = __float2bfloat16(0.f);
                cvT[(size_t)bk * 8192 + d * 128 + 127] = __float2bfloat16(0.f);
            }
            return;
        }
        float sk = 0.f, sv = 0.f;
        int base = b * cS + n * 16 + jg * 8;
        #pragma unroll
        for (int j = 0; j < 8; ++j) {
            size_t o = (size_t)(base + j) * 256 + kv * 64 + d;
            sk += k[o]; sv += v[o];
        }
        redk[jg][d] = sk; redv[jg][d] = sv;
        __syncthreads();
        if (jg == 0) {
            float tk = redk[0][d] + redk[1][d] + redk[2][d] + redk[3][d];
            float tv = redv[0][d] + redv[1][d] + redv[2][d] + redv[3][d];
            ck[(size_t)bk * 8192 + n * 64 + d] = __float2bfloat16(tk * (1.f / 32.f));
            cvT[(size_t)bk * 8192 + d * 128 + n] = __float2bfloat16(tv * (1.f / 32.f));
        }
    } else {
        // ---- blockmeans: importance inputs ----
        int i2 = idx - 1280;
        int m = i2 & 63; int kvb = i2 >> 6; int kv = kvb & 3; int b = kvb >> 2;
        int jg = t >> 6, d = t & 63;
        float sk = 0.f, sq = 0.f;
        #pragma unroll
        for (int j = 0; j < 8; ++j) {
            int row = m * 32 + jg * 8 + j;
            sk += k[(size_t)(b * cS + row) * 256 + kv * 64 + d];
            size_t tb = (size_t)(b * cS + row) * 1024 + kv * 256 + d;
            sq += q[tb] + q[tb + 64] + q[tb + 128] + q[tb + 192];
        }
        redk[jg][d] = sk; redv[jg][d] = sq;
        __syncthreads();
        if (jg == 0) {
            size_t o = ((size_t)(b * cHKV + kv) * cNB + m) * 64 + d;
            kbm[o] = (redk[0][d] + redk[1][d] + redk[2][d] + redk[3][d]) * (1.f / 32.f);
            qs[o]  = (redv[0][d] + redv[1][d] + redv[2][d] + redv[3][d]) * (1.f / 32.f);
        }
    }
}

// ---------------- compressed attention, MFMA flash (reads pre-scaled qb16; writes att16c = bf16(g0*oc)) ----------------
__global__ __launch_bounds__(256) void k_cmp_attn(const bft* __restrict__ qb16, const bft* __restrict__ ck,
                                                  const bft* __restrict__ cvT, const float* __restrict__ gates,
                                                  bft* __restrict__ att) {
    __shared__ __align__(16) bft Qs[256 * 64];
    __shared__ __align__(16) bft Ks[128 * 64];
    __shared__ __align__(16) bft VTs[64 * 128];
    __shared__ __align__(16) bft Ps[4 * 16 * 128];
    int idx = blockIdx.x;
    int chunk = idx & 31; int bk = idx >> 5; int kv = bk & 3; int b = bk >> 2;
    int tid = threadIdx.x;
    // stage Q via GL16 from pre-scaled bf16 (pre-swizzled source); r in [0,256), hh in [0,4)
    #pragma unroll
    for (int c = 0; c < 8; ++c) {
        int p = c * 256 + tid; int r = p >> 3, s = p & 7;
        int hh = r >> 6, toff = r & 63;
        const bft* src = qb16 + ((size_t)(b * cS + chunk * 64 + toff)) * 1024 + (kv * 4 + hh) * 64 + ((s ^ (r & 7)) * 8);
        GL16(src, (char*)Qs + p * 16);
    }
    if (tid < 128) {
        int r = tid;
        const bf16x8* src = (const bf16x8*)(ck + (size_t)bk * 8192 + r * 64);
        #pragma unroll
        for (int s = 0; s < 8; ++s)
            *(bf16x8*)((char*)Ks + r * 128 + ((s ^ (r & 7)) * 16)) = src[s];
    }
    if (tid < 64) {
        int r = tid;
        const bf16x8* src = (const bf16x8*)(cvT + (size_t)bk * 8192 + r * 128);
        #pragma unroll
        for (int s = 0; s < 16; ++s)
            *(bf16x8*)((char*)VTs + r * 256 + ((s ^ (r & 7)) * 16)) = src[s];
    }
    __syncthreads();

    int w = tid >> 6, lane = tid & 63, lrow = lane & 15, lk = lane >> 4;
    int hg = kv * cGQ + w;
    #pragma unroll
    for (int rt = 0; rt < 4; ++rt) {
        int rowb = w * 64 + rt * 16;
        bf16x8 aq[2];
        #pragma unroll
        for (int kh = 0; kh < 2; ++kh) {
            int r = rowb + lrow;
            aq[kh] = *(const bf16x8*)((const char*)Qs + r * 128 + (((kh * 4 + lk) ^ (r & 7)) * 16));
        }
        f32x4 sa[8];
        #pragma unroll
        for (int nt = 0; nt < 8; ++nt) {
            sa[nt] = (f32x4)0.f;
            #pragma unroll
            for (int kh = 0; kh < 2; ++kh) {
                int kr = nt * 16 + lrow;
                bf16x8 bv_ = *(const bf16x8*)((const char*)Ks + kr * 128 + (((kh * 4 + lk) ^ (kr & 7)) * 16));
                sa[nt] = __builtin_amdgcn_mfma_f32_16x16x32_bf16(aq[kh], bv_, sa[nt], 0, 0, 0);
            }
        }
        float mrow[4], srow[4]; int nv[4];
        #pragma unroll
        for (int r = 0; r < 4; ++r) {
            int s_abs = chunk * 64 + rt * 16 + lk * 4 + r;
            nv[r] = (s_abs >= 31) ? (((s_abs - 31) >> 4) + 1) : 0;
            mrow[r] = -INFINITY; srow[r] = 0.f;
        }
        #pragma unroll
        for (int nt = 0; nt < 8; ++nt) {
            int key = nt * 16 + lrow;
            #pragma unroll
            for (int r = 0; r < 4; ++r) {
                float sc = sa[nt][r];   // qb16 pre-scaled by 1/8
                if (key < nv[r]) mrow[r] = fmaxf(mrow[r], sc);
            }
        }
        #pragma unroll
        for (int r = 0; r < 4; ++r) {
            #pragma unroll
            for (int o = 8; o; o >>= 1) mrow[r] = fmaxf(mrow[r], __shfl_xor(mrow[r], o));
        }
        #pragma unroll
        for (int nt = 0; nt < 8; ++nt) {
            int key = nt * 16 + lrow;
            #pragma unroll
            for (int r = 0; r < 4; ++r) {
                float sc = sa[nt][r];
                float p = (key < nv[r]) ? __expf(sc - mrow[r]) : 0.f;
                srow[r] += p;
                int rit = lk * 4 + r;
                *(bft*)((char*)Ps + w * 4096 + rit * 256 + ((((key >> 3) ^ (rit & 7))) * 16) + (key & 7) * 2) =
                    __float2bfloat16(p);
            }
        }
        #pragma unroll
        for (int r = 0; r < 4; ++r) {
            #pragma unroll
            for (int o = 8; o; o >>= 1) srow[r] += __shfl_xor(srow[r], o);
        }
        f32x4 oa[4];
        #pragma unroll
        for (int dt = 0; dt < 4; ++dt) oa[dt] = (f32x4)0.f;
        #pragma unroll
        for (int kc = 0; kc < 4; ++kc) {
            bf16x8 pa = *(const bf16x8*)((const char*)Ps + w * 4096 + lrow * 256 + (((kc * 4 + lk) ^ (lrow & 7)) * 16));
            #pragma unroll
            for (int dt = 0; dt < 4; ++dt) {
                int vr = dt * 16 + lrow;
                bf16x8 vb = *(const bf16x8*)((const char*)VTs + vr * 256 + (((kc * 4 + lk) ^ (vr & 7)) * 16));
                oa[dt] = __builtin_amdgcn_mfma_f32_16x16x32_bf16(pa, vb, oa[dt], 0, 0, 0);
            }
        }
        float inv[4]; int toks[4];
        #pragma unroll
        for (int r = 0; r < 4; ++r) {
            int tok = chunk * 64 + rt * 16 + lk * 4 + r;
            toks[r] = tok;
            float g0 = gates[((size_t)(b * cS + tok)) * 48 + hg * 3 + 0];
            inv[r] = (srow[r] > 0.f) ? (g0 / srow[r]) : 0.f;
        }
        #pragma unroll
        for (int dt = 0; dt < 4; ++dt)
            #pragma unroll
            for (int r = 0; r < 4; ++r)
                att[((size_t)(b * cS + toks[r])) * 1024 + hg * 64 + dt * 16 + lrow] = __float2bfloat16(oa[dt][r] * inv[r]);
    }
}

// ---------------- fused selected + window attention: KVBLK=32, swapped QK^T, packed P,
// ---------------- triple-buffered K/V, counted-vmcnt pipeline. 1024 blocks x 128 thr (head-pair split):
// ---------------- 4 independent 2-wave blocks/CU + balanced n-mix quadrant mapping ----------------
__global__ __launch_bounds__(128) void k_selwin(const bft* __restrict__ qb16, const bft* __restrict__ kb16,
                                                const bft* __restrict__ vT16, const int* __restrict__ sel,
                                                const float* __restrict__ gates, const bft* __restrict__ attb,
                                                bft* __restrict__ att16) {
    __shared__ __align__(16) bft Qs[64 * 64];
    __shared__ __align__(16) bft Ks[3][32 * 64];
    __shared__ __align__(16) bft Vs[3][64 * 32];
    __shared__ __align__(16) bft Ps[2][32 * 32];
    __shared__ int msL[40];
    __shared__ int nmS[2];
    // balanced bijective decode: quadrant q=(b,hp), group g=(kv,t); n = t or 63-t by quadrant
    int raw = blockIdx.x;
    int q_ = raw >> 8, g_ = raw & 255;
    int kv = g_ >> 6, t_ = g_ & 63;
    int n = ((q_ == 1) || (q_ == 2)) ? (63 - t_) : t_;
    int b = q_ >> 1, hp = q_ & 1;
    int bkv = b * 4 + kv;
    int tid = threadIdx.x;
    int w = tid >> 6, lane = tid & 63, lrow = lane & 15, lk = lane >> 4;
    int h = kv * 4 + hp * 2 + w;

    // stage Q: 64 rows (2 heads x 32 tokens) x 8 slots = 512 positions, 128 thr x 4 iters
    #pragma unroll
    for (int c = 0; c < 4; ++c) {
        int p = c * 128 + tid; int r = p >> 3, s = p & 7;
        const bft* src = qb16 + ((size_t)(b * cS + n * 32 + (r & 31))) * 1024 + (kv * 4 + hp * 2 + (r >> 5)) * 64 + ((s ^ (r & 7)) * 8);
        GL16(src, (char*)Qs + p * 16);
    }
    // stage K0/V0: 256 positions each, 128 thr x 2 iters
    #pragma unroll
    for (int it = 0; it < 2; ++it) {
        int p = it * 128 + tid;
        int row = p >> 3, s = p & 7;
        const bft* srck = kb16 + ((size_t)bkv * 2048 + n * 32 + row) * 64 + ((s ^ (row & 7)) * 8);
        GL16(srck, (char*)Ks[0] + p * 16);
        int rowv = p >> 2, g3 = p & 3;
        const bft* srcv = vT16 + ((size_t)bkv * 64 + rowv) * 2048 + n * 32 + ((g3 ^ (rowv & 3)) * 8);
        GL16(srcv, (char*)Vs[0] + p * 16);
    }
    if (tid == 0) {
        const int* selp = sel + ((size_t)bkv * cNB + n) * cTB;
        int nm = 0;
        #pragma unroll
        for (int t = 0; t < cTB; ++t) { int m = selp[t]; if (m <= n) msL[nm++] = m; }
        nmS[0] = nm;
        int m0 = (n > 16) ? (n - 16) : 0;
        for (int m = m0; m <= n; ++m) msL[nm++] = m;
        nmS[1] = nm;
    }
    // FULL drain (vmcnt AND lgkmcnt) before cross-wave read of msL/nmS.
    __syncthreads();

    int p1 = nmS[0], nm = nmS[1];
    bf16x8 qf[2][2];
    #pragma unroll
    for (int qt = 0; qt < 2; ++qt)
        #pragma unroll
        for (int kh = 0; kh < 2; ++kh) {
            int r = w * 32 + qt * 16 + lrow;
            qf[qt][kh] = *(const bf16x8*)((const char*)Qs + r * 128 + (((kh * 4 + lk) ^ (r & 7)) * 16));
        }

    f32x4 oa[2][4], accf[2][4];
    float sacc[2] = {0.f, 0.f};
    #pragma unroll
    for (int qt = 0; qt < 2; ++qt)
        #pragma unroll
        for (int dt = 0; dt < 4; ++dt) { oa[qt][dt] = (f32x4)0.f; accf[qt][dt] = (f32x4)0.f; }

    for (int i = 0; i < nm; ++i) {
        int buf = i % 3;
        if (i == 0 && nm > 1) {
            int m1 = msL[1];
            #pragma unroll
            for (int it = 0; it < 2; ++it) {
                int p = it * 128 + tid;
                int row = p >> 3, s = p & 7;
                const bft* srck = kb16 + ((size_t)bkv * 2048 + m1 * 32 + row) * 64 + ((s ^ (row & 7)) * 8);
                GL16(srck, (char*)Ks[1] + p * 16);
                int rowv = p >> 2, g3 = p & 3;
                const bft* srcv = vT16 + ((size_t)bkv * 64 + rowv) * 2048 + m1 * 32 + ((g3 ^ (rowv & 3)) * 8);
                GL16(srcv, (char*)Vs[1] + p * 16);
            }
        }
        if (i + 2 < nm) {
            int m2 = msL[i + 2]; int sl = (i + 2) % 3;
            #pragma unroll
            for (int it = 0; it < 2; ++it) {
                int p = it * 128 + tid;
                int row = p >> 3, s = p & 7;
                const bft* srck = kb16 + ((size_t)bkv * 2048 + m2 * 32 + row) * 64 + ((s ^ (row & 7)) * 8);
                GL16(srck, (char*)Ks[sl] + p * 16);
                int rowv = p >> 2, g3 = p & 3;
                const bft* srcv = vT16 + ((size_t)bkv * 64 + rowv) * 2048 + m2 * 32 + ((g3 ^ (rowv & 3)) * 8);
                GL16(srcv, (char*)Vs[sl] + p * 16);
            }
        }
        int m = msL[i];
        bool diag = (m == n);
        #pragma unroll
        for (int qt = 0; qt < 2; ++qt) {
            int q = qt * 16 + lrow;
            #pragma unroll
            for (int kt = 0; kt < 2; ++kt) {
                f32x4 a = (f32x4)0.f;
                #pragma unroll
                for (int kh = 0; kh < 2; ++kh) {
                    int kr = kt * 16 + lrow;
                    bf16x8 ak = *(const bf16x8*)((const char*)Ks[buf] + kr * 128 + (((kh * 4 + lk) ^ (kr & 7)) * 16));
                    a = __builtin_amdgcn_mfma_f32_16x16x32_bf16(ak, qf[qt][kh], a, 0, 0, 0);
                }
                int k0 = kt * 16 + lk * 4;
                float p0 = (!diag || k0 <= q)     ? __expf(a[0]) : 0.f;
                float p1v = (!diag || k0 + 1 <= q) ? __expf(a[1]) : 0.f;
                float p2 = (!diag || k0 + 2 <= q) ? __expf(a[2]) : 0.f;
                float p3 = (!diag || k0 + 3 <= q) ? __expf(a[3]) : 0.f;
                sacc[qt] += p0 + p1v + p2 + p3;
                bft h0 = __float2bfloat16(p0), h1 = __float2bfloat16(p1v);
                bft h2 = __float2bfloat16(p2), h3 = __float2bfloat16(p3);
                unsigned int w0 = ((unsigned int)(*(unsigned short*)&h1) << 16) | (unsigned int)(*(unsigned short*)&h0);
                unsigned int w1 = ((unsigned int)(*(unsigned short*)&h3) << 16) | (unsigned int)(*(unsigned short*)&h2);
                int g = kt * 2 + (lk >> 1);
                *(uint2*)((char*)Ps[w] + q * 64 + ((g ^ (q & 3)) * 16) + (lk & 1) * 8) = make_uint2(w0, w1);
            }
        }
        #pragma unroll
        for (int qt = 0; qt < 2; ++qt) {
            int q = qt * 16 + lrow;
            bf16x8 pa = *(const bf16x8*)((const char*)Ps[w] + q * 64 + ((lk ^ (q & 3)) * 16));
            #pragma unroll
            for (int dt = 0; dt < 4; ++dt) {
                int vr = dt * 16 + lrow;
                bf16x8 vb = *(const bf16x8*)((const char*)Vs[buf] + vr * 64 + ((lk ^ (vr & 3)) * 16));
                oa[qt][dt] = __builtin_amdgcn_mfma_f32_16x16x32_bf16(pa, vb, oa[qt][dt], 0, 0, 0);
            }
        }
        if (i == p1 - 1 || i == nm - 1) {
            int gi = (i == p1 - 1) ? 1 : 2;
            #pragma unroll
            for (int qt = 0; qt < 2; ++qt) {
                float s2 = sacc[qt];
                s2 += __shfl_xor(s2, 16); s2 += __shfl_xor(s2, 32);
                #pragma unroll
                for (int r = 0; r < 4; ++r) {
                    float l = __shfl(s2, lk * 4 + r);
                    int tok = n * 32 + qt * 16 + lk * 4 + r;
                    float g = gates[((size_t)(b * cS + tok)) * 48 + h * 3 + gi];
                    float f = g / l;
                    #pragma unroll
                    for (int dt = 0; dt < 4; ++dt) accf[qt][dt][r] += f * oa[qt][dt][r];
                }
                sacc[qt] = 0.f;
                #pragma unroll
                for (int dt = 0; dt < 4; ++dt) oa[qt][dt] = (f32x4)0.f;
            }
        }
        if (i + 1 < nm) {
            if (i + 2 < nm) { asm volatile("s_waitcnt vmcnt(4)" ::: "memory"); }
            else            { asm volatile("s_waitcnt vmcnt(0)" ::: "memory"); }
            FENCE; __builtin_amdgcn_s_barrier(); FENCE;
        }
    }
    #pragma unroll
    for (int qt = 0; qt < 2; ++qt)
        #pragma unroll
        for (int dt = 0; dt < 4; ++dt)
            #pragma unroll
            for (int r = 0; r < 4; ++r) {
                int tok = n * 32 + qt * 16 + lk * 4 + r;
                size_t a_ = ((size_t)(b * cS + tok)) * 1024 + h * 64 + dt * 16 + lrow;
                att16[a_] = __float2bfloat16(__bfloat162float(attb[a_]) + accf[qt][dt][r]);
            }
}

// ---------------- importance + top-16 (jax.lax.top_k tie rule: lower index wins) ----------------
__global__ __launch_bounds__(64) void k_topk(const float* __restrict__ qs, const float* __restrict__ kbm,
                                             int* __restrict__ sel) {
    int idx = blockIdx.x; int n = idx & 63; int kvb = idx >> 6; int kv = kvb & 3; int b = kvb >> 2;
    int lane = threadIdx.x;
    __shared__ float qrow[64];
    size_t base = (size_t)(b * cHKV + kv) * cNB;
    qrow[lane] = qs[(base + n) * 64 + lane];
    __syncthreads();
    float val;
    if (lane <= n) {
        const float* kb = kbm + (base + lane) * 64;
        float s_ = 0.f;
        for (int d = 0; d < 64; ++d) s_ += qrow[d] * kb[d];
        val = (lane == n) ? 1e9f : s_;
    } else val = -1e9f;
    int* so = sel + (base + n) * cTB;
    float v_ = val;
    for (int t = 0; t < cTB; ++t) {
        float bv = v_; int bi = lane;
        #pragma unroll
        for (int o = 32; o; o >>= 1) {
            float ov = __shfl_xor(bv, o); int oi = __shfl_xor(bi, o);
            if (ov > bv || (ov == bv && oi < bi)) { bv = ov; bi = oi; }
        }
        if (lane == 0) so[t] = bi;
        if (lane == bi) v_ = -INFINITY;
    }
}

extern "C" void kernel_launch(void* const* d_in, const int* in_sizes, int n_in,
                              void* d_out, int out_size, void* d_ws, size_t ws_size,
                              hipStream_t stream) {
    const float* x    = (const float*)d_in[0];
    const float* ln1w = (const float*)d_in[1];
    const float* ln1b = (const float*)d_in[2];
    const float* wq   = (const float*)d_in[3];
    const float* bq   = (const float*)d_in[4];
    const float* wk   = (const float*)d_in[5];
    const float* bk   = (const float*)d_in[6];
    const float* wv   = (const float*)d_in[7];
    const float* bv   = (const float*)d_in[8];
    const float* wg   = (const float*)d_in[9];
    const float* bg   = (const float*)d_in[10];
    const float* wo   = (const float*)d_in[11];
    const float* bo   = (const float*)d_in[12];
    const float* ln2w = (const float*)d_in[13];
    const float* ln2b = (const float*)d_in[14];
    const float* w1   = (const float*)d_in[15];
    const float* b1   = (const float*)d_in[16];
    const float* w2   = (const float*)d_in[17];
    const float* b2   = (const float*)d_in[18];

    char* ws = (char*)d_ws;
    const size_t MiB = 1024 * 1024;
    bft*  wcatT = (bft*) (ws);                        // [1664][1024]
    bft*  woT   = (bft*) (ws + 3 * MiB + 256 * 1024); // [1024][1024]
    bft*  w1T   = (bft*) (ws + 5 * MiB + 256 * 1024); // [4096][1024]
    bft*  w2T   = (bft*) (ws + 13 * MiB + 256 * 1024);// [1024][4096]
    bft*  hbuf  = (bft*) (ws + 21 * MiB + 256 * 1024);// [4096][1024] bf16 (LN1/LN2 out; dead during attn)
    float* qbuf = (float*)(ws + 29 * MiB + 256 * 1024);// [4096][1024]
    float* kbuf = (float*)(ws + 45 * MiB + 256 * 1024);// [4096][256]
    float* vbuf = (float*)(ws + 49 * MiB + 256 * 1024);// [4096][256]
    float* gbuf = (float*)(ws + 53 * MiB + 256 * 1024);// [4096][48]
    bft*  ckb   = (bft*)  (ws + 55 * MiB + 256 * 1024);// [8][128][64] bf16
    bft*  cvTb  = (bft*)  (ws + 56 * MiB + 256 * 1024);// [8][64][128] bf16
    float* kbmb = (float*)(ws + 57 * MiB + 256 * 1024);
    float* qsb  = (float*)(ws + 57 * MiB + 384 * 1024);
    int*   selb = (int*)  (ws + 57 * MiB + 512 * 1024);
    bft*  attb16= (bft*) (ws + 58 * MiB);             // [4096][1024] bf16 (g0*oc)
    bft*  att16 = (bft*) (ws + 74 * MiB);             // [4096][1024] bf16
    float* x1b  = (float*)(ws + 82 * MiB);            // [4096][1024] f32
    bft*  zbuf  = (bft*) (ws + 29 * MiB + 256 * 1024);// [4096][4096] bf16, aliases dead qkv region
    bft*  kb16  = (bft*) (ws + 21 * MiB + 256 * 1024);// [8][2048][64] bf16, 2 MiB
    bft*  vT16  = (bft*) (ws + 23 * MiB + 256 * 1024);// [8][64][2048] bf16, 2 MiB
    bft*  qb16  = (bft*) (ws + 82 * MiB);             // [4096][1024] bf16 prescaled, aliases x1b (dead until wo-GEMM)
    // split-K partials for MLP-down: 4 x 8 MiB bf16, placed in regions dead at MLP-down time
    bft*  skp0  = (bft*) (ws);                         // over wcatT/woT/w1T head (dead)
    bft*  skp1  = (bft*) (ws + 21 * MiB + 256 * 1024); // over hbuf (dead after MLP-up)
    bft*  skp2  = (bft*) (ws + 61 * MiB + 256 * 1024); // over attb tail (dead)
    bft*  skp3  = (bft*) (ws + 69 * MiB + 256 * 1024); // over attb/att16 tail (dead)

    dim3 t328(32, 8);
    // fused weight transposes: QKVG (1 launch) + wo/w1/w2 (1 launch)
    k_transpose_qkvg<<<dim3(32, 52), t328, 0, stream>>>(wq, wk, wv, wg, wcatT);
    k_transpose_w3<<<9216, t328, 0, stream>>>(wo, w1, w2, woT, w1T, w2T);
    k_ln<<<4096, 256, 0, stream>>>(x, ln1w, ln1b, hbuf);
    k_gemm<0><<<dim3(13, 32), 256, 0, stream>>>(hbuf, wcatT, 4096, 1664, 1024,
        nullptr, nullptr, nullptr, nullptr, qbuf, kbuf, vbuf, gbuf, bq, bk, bv, bg, qb16);
    // fused KV utilities: kvprep | cmp_kv | blockmeans
    k_kvutil<<<1792, 256, 0, stream>>>(kbuf, vbuf, qbuf, kb16, vT16, ckb, cvTb, kbmb, qsb);
    k_cmp_attn<<<256, 256, 0, stream>>>(qb16, ckb, cvTb, gbuf, attb16);
    k_topk<<<cB * cHKV * cNB, 64, 0, stream>>>(qsb, kbmb, selb);
    k_selwin<<<1024, 128, 0, stream>>>(qb16, kb16, vT16, selb, gbuf, attb16, att16);
    k_gemm<1><<<dim3(8, 32), 256, 0, stream>>>(att16, woT, 4096, 1024, 1024,
        bo, x, x1b, nullptr, nullptr, nullptr, nullptr, nullptr, nullptr, nullptr, nullptr, nullptr, nullptr);
    k_ln<<<4096, 256, 0, stream>>>(x1b, ln2w, ln2b, hbuf);
    // MLP up + GELU: 256^2 8-phase kernel
    k_gemm256_gelu<<<dim3(16, 16), 512, 0, stream>>>(hbuf, w1T, b1, zbuf);
    // MLP down: split-K x4 256^2 8-phase + fused reduce (bias + residual)
    k_gemm256_sk<<<256, 512, 0, stream>>>(zbuf, w2T, skp0, skp1, skp2, skp3);
    k_mlpred<<<2048, 256, 0, stream>>>(skp0, skp1, skp2, skp3, x1b, b2, (float*)d_out);
}

// Round 20
// 258.399 us; speedup vs baseline: 1.0710x; 1.0245x over previous
//
#include <hip/hip_runtime.h>
#include <hip/hip_bf16.h>
#include <math.h>

typedef __hip_bfloat16 bft;
typedef __attribute__((ext_vector_type(8))) short bf16x8;
typedef __attribute__((ext_vector_type(4))) float f32x4;

constexpr int cB = 2, cS = 2048, cD = 1024, cH = 16, cHKV = 4, cGQ = 4, cHD = 64;
constexpr int cBS = 32, cTB = 16, cNB = 64, cNC = 127;

#define GL16(gp, lp) __builtin_amdgcn_global_load_lds((const __attribute__((address_space(1))) void*)(gp), (__attribute__((address_space(3))) void*)(lp), 16, 0, 0)
#define FENCE asm volatile("" ::: "memory")

__device__ __forceinline__ float bf2f(short h) {
    return __uint_as_float(((unsigned int)(unsigned short)h) << 16);
}

// ---------------- mega-prologue: LN1 | QKVG transpose | wo/w1/w2 transpose (5 launches -> 1) ----------------
// blocks [0,4096): LN1 row; [4096,5760): qkvg; [5760,14976): w3
__global__ __launch_bounds__(256) void k_prolog(const float* __restrict__ x, const float* __restrict__ ln1w,
                                                const float* __restrict__ ln1b, bft* __restrict__ hbuf,
                                                const float* __restrict__ wq, const float* __restrict__ wk,
                                                const float* __restrict__ wv, const float* __restrict__ wg,
                                                bft* __restrict__ wcatT,
                                                const float* __restrict__ wo, const float* __restrict__ w1,
                                                const float* __restrict__ w2,
                                                bft* __restrict__ woT, bft* __restrict__ w1T, bft* __restrict__ w2T) {
    __shared__ float tile[32][33];
    __shared__ float red[8];
    int idx = blockIdx.x;
    int t = threadIdx.x;
    if (idx < 4096) {
        int row = idx;
        const float4* xr = (const float4*)(x + (size_t)row * cD);
        float4 v = xr[t];
        float s = v.x + v.y + v.z + v.w;
        #pragma unroll
        for (int o = 32; o; o >>= 1) s += __shfl_xor(s, o);
        int wid = t >> 6, lane = t & 63;
        if (lane == 0) red[wid] = s;
        __syncthreads();
        float mean = (red[0] + red[1] + red[2] + red[3]) * (1.f / cD);
        float dx = v.x - mean, dy = v.y - mean, dz = v.z - mean, dw = v.w - mean;
        float sq = dx * dx + dy * dy + dz * dz + dw * dw;
        #pragma unroll
        for (int o = 32; o; o >>= 1) sq += __shfl_xor(sq, o);
        if (lane == 0) red[4 + wid] = sq;
        __syncthreads();
        float var = (red[4] + red[5] + red[6] + red[7]) * (1.f / cD);
        float rstd = rsqrtf(var + 1e-5f);
        float4 wv_ = ((const float4*)ln1w)[t];
        float4 bv = ((const float4*)ln1b)[t];
        bft* o_ = hbuf + (size_t)row * cD + t * 4;
        o_[0] = __float2bfloat16(dx * rstd * wv_.x + bv.x);
        o_[1] = __float2bfloat16(dy * rstd * wv_.y + bv.y);
        o_[2] = __float2bfloat16(dz * rstd * wv_.z + bv.z);
        o_[3] = __float2bfloat16(dw * rstd * wv_.w + bv.w);
    } else if (idx < 5760) {
        int r = idx - 4096;
        int kb = (r & 31) * 32, nb = (r >> 5) * 32;   // nb in [0,1664)
        const float* src; int N, off;
        if (nb < 1024)      { src = wq; N = 1024; off = 0; }
        else if (nb < 1280) { src = wk; N = 256;  off = 1024; }
        else if (nb < 1536) { src = wv; N = 256;  off = 1280; }
        else                { src = wg; N = 48;   off = 1536; }
        int tx = t & 31, ty = t >> 5; // 32 x 8
        #pragma unroll
        for (int i = 0; i < 32; i += 8) {
            int k = kb + ty + i, n = nb - off + tx;
            tile[ty + i][tx] = (n < N) ? src[(size_t)k * N + n] : 0.f;
        }
        __syncthreads();
        #pragma unroll
        for (int i = 0; i < 32; i += 8) {
            int n = nb + ty + i, k = kb + tx;
            wcatT[(size_t)n * 1024 + k] = __float2bfloat16(tile[tx][ty + i]);
        }
    } else {
        int r0 = idx - 5760;
        const float* src; bft* dst; int K, N, kb, nb;
        if (r0 < 1024)      { src = wo; dst = woT; K = 1024; N = 1024; kb = (r0 & 31) * 32;  nb = (r0 >> 5) * 32; }
        else if (r0 < 5120) { int r = r0 - 1024; src = w1; dst = w1T; K = 1024; N = 4096; kb = (r & 31) * 32;  nb = (r >> 5) * 32; }
        else                { int r = r0 - 5120; src = w2; dst = w2T; K = 4096; N = 1024; kb = (r & 127) * 32; nb = (r >> 7) * 32; }
        int tx = t & 31, ty = t >> 5; // 32 x 8
        #pragma unroll
        for (int i = 0; i < 32; i += 8) {
            int k = kb + ty + i, n = nb + tx;
            tile[ty + i][tx] = src[(size_t)k * N + n];
        }
        __syncthreads();
        #pragma unroll
        for (int i = 0; i < 32; i += 8) {
            int n = nb + ty + i, k = kb + tx;
            dst[(size_t)n * K + k] = __float2bfloat16(tile[tx][ty + i]);
        }
    }
}

// ---------------- LayerNorm (fp32 in, bf16 out) ----------------
__global__ __launch_bounds__(256) void k_ln(const float* __restrict__ src, const float* __restrict__ w,
                                            const float* __restrict__ b, bft* __restrict__ dst) {
    int row = blockIdx.x; int t = threadIdx.x;
    const float4* xr = (const float4*)(src + (size_t)row * cD);
    float4 v = xr[t];
    float s = v.x + v.y + v.z + v.w;
    #pragma unroll
    for (int o = 32; o; o >>= 1) s += __shfl_xor(s, o);
    __shared__ float red[8];
    int wid = t >> 6, lane = t & 63;
    if (lane == 0) red[wid] = s;
    __syncthreads();
    float mean = (red[0] + red[1] + red[2] + red[3]) * (1.f / cD);
    float dx = v.x - mean, dy = v.y - mean, dz = v.z - mean, dw = v.w - mean;
    float sq = dx * dx + dy * dy + dz * dz + dw * dw;
    #pragma unroll
    for (int o = 32; o; o >>= 1) sq += __shfl_xor(sq, o);
    if (lane == 0) red[4 + wid] = sq;
    __syncthreads();
    float var = (red[4] + red[5] + red[6] + red[7]) * (1.f / cD);
    float rstd = rsqrtf(var + 1e-5f);
    float4 wv = ((const float4*)w)[t];
    float4 bv = ((const float4*)b)[t];
    bft* o_ = dst + (size_t)row * cD + t * 4;
    o_[0] = __float2bfloat16(dx * rstd * wv.x + bv.x);
    o_[1] = __float2bfloat16(dy * rstd * wv.y + bv.y);
    o_[2] = __float2bfloat16(dz * rstd * wv.z + bv.z);
    o_[3] = __float2bfloat16(dw * rstd * wv.w + bv.w);
}

// ---------------- MFMA GEMM 128^2 (m97 structure + XCD swizzle): C = A * Bt^T ----------------
template<int MODE>
__global__ __launch_bounds__(256) void k_gemm(const bft* __restrict__ A, const bft* __restrict__ Bt,
        int M, int N, int K,
        const float* __restrict__ bias, const float* __restrict__ add,
        float* __restrict__ outf, bft* __restrict__ outb,
        float* __restrict__ oq, float* __restrict__ okk, float* __restrict__ ovv, float* __restrict__ og,
        const float* __restrict__ bq, const float* __restrict__ bk,
        const float* __restrict__ bv, const float* __restrict__ bg,
        bft* __restrict__ oqb) {
    __shared__ __align__(16) bft As[128 * 64];
    __shared__ __align__(16) bft Bs[128 * 64];
    int tid = threadIdx.x;
    int nwg = gridDim.x * gridDim.y;
    int bid = blockIdx.y * gridDim.x + blockIdx.x;
    int q8 = nwg >> 3;
    int wg = (bid & 7) * q8 + (bid >> 3);
    int bx = wg % gridDim.x, by = wg / gridDim.x;
    int m0 = by * 128, n0 = bx * 128;
    int lane = tid & 63, wid = tid >> 6;
    int wr = wid >> 1, wc = wid & 1;
    int lrow = lane & 15, lk = lane >> 4;
    f32x4 acc[4][4];
    #pragma unroll
    for (int i = 0; i < 4; ++i)
        #pragma unroll
        for (int j = 0; j < 4; ++j) acc[i][j] = (f32x4)0.f;

    for (int kt = 0; kt < K; kt += 64) {
        #pragma unroll
        for (int sh = 0; sh < 4; ++sh) {
            int p = sh * 256 + tid;
            int row = p >> 3;
            int slot = p & 7;
            int ss = slot ^ (row & 7);
            const bft* ga = A + (size_t)(m0 + row) * K + kt + ss * 8;
            const bft* gb = Bt + (size_t)(n0 + row) * K + kt + ss * 8;
            GL16(ga, (char*)As + p * 16);
            GL16(gb, (char*)Bs + p * 16);
        }
        __syncthreads();
        #pragma unroll
        for (int kh = 0; kh < 2; ++kh) {
            bf16x8 af[4], bfv[4];
            #pragma unroll
            for (int mi = 0; mi < 4; ++mi) {
                int row = wr * 64 + mi * 16 + lrow;
                int c8 = kh * 4 + lk;
                af[mi] = *(const bf16x8*)((const char*)As + row * 128 + ((c8 ^ (row & 7)) * 16));
            }
            #pragma unroll
            for (int ni = 0; ni < 4; ++ni) {
                int row = wc * 64 + ni * 16 + lrow;
                int c8 = kh * 4 + lk;
                bfv[ni] = *(const bf16x8*)((const char*)Bs + row * 128 + ((c8 ^ (row & 7)) * 16));
            }
            #pragma unroll
            for (int mi = 0; mi < 4; ++mi)
                #pragma unroll
                for (int ni = 0; ni < 4; ++ni)
                    acc[mi][ni] = __builtin_amdgcn_mfma_f32_16x16x32_bf16(af[mi], bfv[ni], acc[mi][ni], 0, 0, 0);
        }
        __syncthreads();
    }
    #pragma unroll
    for (int mi = 0; mi < 4; ++mi)
        #pragma unroll
        for (int ni = 0; ni < 4; ++ni)
            #pragma unroll
            for (int r = 0; r < 4; ++r) {
                int gr = m0 + wr * 64 + mi * 16 + lk * 4 + r;
                int gc = n0 + wc * 64 + ni * 16 + lrow;
                float val = acc[mi][ni][r];
                if (MODE == 0) {
                    if (gc < 1024) {
                        float qv2 = val + bq[gc];
                        oq[(size_t)gr * 1024 + gc] = qv2;
                        oqb[(size_t)gr * 1024 + gc] = __float2bfloat16(qv2 * 0.125f);
                    }
                    else if (gc < 1280) okk[(size_t)gr * 256 + gc - 1024] = val + bk[gc - 1024];
                    else if (gc < 1536) ovv[(size_t)gr * 256 + gc - 1280] = val + bv[gc - 1280];
                    else if (gc < 1584) {
                        float t2 = val + bg[gc - 1536];
                        og[(size_t)gr * 48 + gc - 1536] = 1.f / (1.f + __expf(-t2));
                    }
                } else if (MODE == 1) {
                    size_t o = (size_t)gr * N + gc;
                    outf[o] = val + bias[gc] + add[o];
                } else if (MODE == 2) {
                    float t2 = val + bias[gc];
                    float ge = 0.5f * t2 * (1.f + erff(t2 * 0.70710678118654752f));
                    outb[(size_t)gr * N + gc] = __float2bfloat16(ge);
                } else {
                    size_t o = (size_t)gr * N + gc;
                    outf[o] = val + bias[gc] + add[o];
                }
            }
}

// ---------------- 256^2 8-phase GEMM (T2+T3+T4+T5), fused GELU: zbuf = gelu(hbuf @ w1T^T + b1) ----------------
__global__ __launch_bounds__(512) void k_gemm256_gelu(const bft* __restrict__ A, const bft* __restrict__ Bt,
                                                      const float* __restrict__ bias, bft* __restrict__ outb) {
    constexpr int K = 1024, N = 4096, NT = K / 64;
    __shared__ __align__(16) bft As[2][256 * 64];
    __shared__ __align__(16) bft Bs[2][256 * 64];
    int tid = threadIdx.x;
    int nwg = gridDim.x * gridDim.y;                 // 256
    int bid = blockIdx.y * gridDim.x + blockIdx.x;
    int q8 = nwg >> 3;
    int wg = (bid & 7) * q8 + (bid >> 3);            // bijective XCD swizzle
    int bx = wg % gridDim.x, by = wg / gridDim.x;
    int m0 = by * 256, n0 = bx * 256;
    int w = tid >> 6, lane = tid & 63, lrow = lane & 15, lk = lane >> 4;
    int wr = w >> 2, wc = w & 3;
    int l8 = lane >> 3, l7 = lane & 7;
    int ssrc = (l7 ^ l8) * 8;

    auto stageA = [&](int buf, int h, int kt) {
        int rbase = 32 * w + 16 * h;
        const bft* g0 = A + (size_t)(m0 + rbase + l8) * K + kt + ssrc;
        GL16(g0, (char*)As[buf] + rbase * 128 + lane * 16);
        const bft* g1 = A + (size_t)(m0 + rbase + 8 + l8) * K + kt + ssrc;
        GL16(g1, (char*)As[buf] + rbase * 128 + 1024 + lane * 16);
    };
    auto stageB = [&](int buf, int h, int kt) {
        int rbase = 32 * w + 16 * h;
        const bft* g0 = Bt + (size_t)(n0 + rbase + l8) * K + kt + ssrc;
        GL16(g0, (char*)Bs[buf] + rbase * 128 + lane * 16);
        const bft* g1 = Bt + (size_t)(n0 + rbase + 8 + l8) * K + kt + ssrc;
        GL16(g1, (char*)Bs[buf] + rbase * 128 + 1024 + lane * 16);
    };
    auto ldA = [&](int buf, int mi, int kk) {
        int r = wr * 128 + mi * 16 + lrow;
        return *(const bf16x8*)((const char*)As[buf] + r * 128 + (((kk * 4 + lk) ^ (r & 7)) * 16));
    };
    auto ldB = [&](int buf, int ni, int kk) {
        int r = wc * 64 + ni * 16 + lrow;
        return *(const bf16x8*)((const char*)Bs[buf] + r * 128 + (((kk * 4 + lk) ^ (r & 7)) * 16));
    };

    f32x4 acc[8][4];
    #pragma unroll
    for (int i = 0; i < 8; ++i)
        #pragma unroll
        for (int j = 0; j < 4; ++j) acc[i][j] = (f32x4)0.f;

    stageA(0, 0, 0); stageB(0, 0, 0); stageA(0, 1, 0); stageB(0, 1, 0);
    asm volatile("s_waitcnt vmcnt(4)" ::: "memory");
    FENCE; __builtin_amdgcn_s_barrier(); FENCE;

    bf16x8 aE[4][2], aO[4][2], bE[2][2], bO[2][2];
    for (int t = 0; t < NT; ++t) {
        int cur = t & 1, nxt = cur ^ 1;
        int ktn = (t + 1) * 64;
        bool pre = (t + 1 < NT);
        #pragma unroll
        for (int i = 0; i < 4; ++i)
            #pragma unroll
            for (int kk = 0; kk < 2; ++kk) aE[i][kk] = ldA(cur, 2 * i, kk);
        #pragma unroll
        for (int j = 0; j < 2; ++j)
            #pragma unroll
            for (int kk = 0; kk < 2; ++kk) bE[j][kk] = ldB(cur, 2 * j, kk);
        if (pre) { stageA(nxt, 0, ktn); asm volatile("s_waitcnt vmcnt(2)" ::: "memory"); }
        else     {                       asm volatile("s_waitcnt vmcnt(0)" ::: "memory"); }
        FENCE; __builtin_amdgcn_s_barrier(); FENCE;
        __builtin_amdgcn_s_setprio(1);
        #pragma unroll
        for (int i = 0; i < 4; ++i)
            #pragma unroll
            for (int j = 0; j < 2; ++j)
                #pragma unroll
                for (int kk = 0; kk < 2; ++kk)
                    acc[2 * i][2 * j] = __builtin_amdgcn_mfma_f32_16x16x32_bf16(aE[i][kk], bE[j][kk], acc[2 * i][2 * j], 0, 0, 0);
        __builtin_amdgcn_s_setprio(0);
        FENCE; __builtin_amdgcn_s_barrier(); FENCE;
        #pragma unroll
        for (int j = 0; j < 2; ++j)
            #pragma unroll
            for (int kk = 0; kk < 2; ++kk) bO[j][kk] = ldB(cur, 2 * j + 1, kk);
        if (pre) stageB(nxt, 0, ktn);
        FENCE; __builtin_amdgcn_s_barrier(); FENCE;
        __builtin_amdgcn_s_setprio(1);
        #pragma unroll
        for (int i = 0; i < 4; ++i)
            #pragma unroll
            for (int j = 0; j < 2; ++j)
                #pragma unroll
                for (int kk = 0; kk < 2; ++kk)
                    acc[2 * i][2 * j + 1] = __builtin_amdgcn_mfma_f32_16x16x32_bf16(aE[i][kk], bO[j][kk], acc[2 * i][2 * j + 1], 0, 0, 0);
        __builtin_amdgcn_s_setprio(0);
        FENCE; __builtin_amdgcn_s_barrier(); FENCE;
        #pragma unroll
        for (int i = 0; i < 4; ++i)
            #pragma unroll
            for (int kk = 0; kk < 2; ++kk) aO[i][kk] = ldA(cur, 2 * i + 1, kk);
        if (pre) stageA(nxt, 1, ktn);
        FENCE; __builtin_amdgcn_s_barrier(); FENCE;
        __builtin_amdgcn_s_setprio(1);
        #pragma unroll
        for (int i = 0; i < 4; ++i)
            #pragma unroll
            for (int j = 0; j < 2; ++j)
                #pragma unroll
                for (int kk = 0; kk < 2; ++kk)
                    acc[2 * i + 1][2 * j] = __builtin_amdgcn_mfma_f32_16x16x32_bf16(aO[i][kk], bE[j][kk], acc[2 * i + 1][2 * j], 0, 0, 0);
        __builtin_amdgcn_s_setprio(0);
        FENCE; __builtin_amdgcn_s_barrier(); FENCE;
        if (pre) { stageB(nxt, 1, ktn); asm volatile("s_waitcnt vmcnt(4)" ::: "memory"); }
        FENCE; __builtin_amdgcn_s_barrier(); FENCE;
        __builtin_amdgcn_s_setprio(1);
        #pragma unroll
        for (int i = 0; i < 4; ++i)
            #pragma unroll
            for (int j = 0; j < 2; ++j)
                #pragma unroll
                for (int kk = 0; kk < 2; ++kk)
                    acc[2 * i + 1][2 * j + 1] = __builtin_amdgcn_mfma_f32_16x16x32_bf16(aO[i][kk], bO[j][kk], acc[2 * i + 1][2 * j + 1], 0, 0, 0);
        __builtin_amdgcn_s_setprio(0);
        FENCE; __builtin_amdgcn_s_barrier(); FENCE;
    }
    #pragma unroll
    for (int mi = 0; mi < 8; ++mi)
        #pragma unroll
        for (int ni = 0; ni < 4; ++ni)
            #pragma unroll
            for (int r = 0; r < 4; ++r) {
                int gr = m0 + wr * 128 + mi * 16 + lk * 4 + r;
                int gc = n0 + wc * 64 + ni * 16 + lrow;
                float t2 = acc[mi][ni][r] + bias[gc];
                float ge = 0.5f * t2 * (1.f + erff(t2 * 0.70710678118654752f));
                outb[(size_t)gr * N + gc] = __float2bfloat16(ge);
            }
}

// ---------------- 256^2 8-phase split-K GEMM for MLP-down: partials = zbuf @ w2T^T (bf16) ----------------
__global__ __launch_bounds__(512) void k_gemm256_sk(const bft* __restrict__ A, const bft* __restrict__ Bt,
                                                    bft* __restrict__ q0, bft* __restrict__ q1,
                                                    bft* __restrict__ q2, bft* __restrict__ q3) {
    constexpr int KT = 4096, N = 1024, NT = 16;
    __shared__ __align__(16) bft As[2][256 * 64];
    __shared__ __align__(16) bft Bs[2][256 * 64];
    int tid = threadIdx.x;
    int flat = blockIdx.x;
    int wg = (flat & 7) * 32 + (flat >> 3);          // bijective XCD swizzle over 256
    int slice = wg >> 6; int rem = wg & 63;
    int m0 = (rem >> 2) * 256, n0 = (rem & 3) * 256;
    int kbase = slice * 1024;
    int w = tid >> 6, lane = tid & 63, lrow = lane & 15, lk = lane >> 4;
    int wr = w >> 2, wc = w & 3;
    int l8 = lane >> 3, l7 = lane & 7;
    int ssrc = (l7 ^ l8) * 8;

    auto stageA = [&](int buf, int h, int kt) {
        int rbase = 32 * w + 16 * h;
        const bft* g0 = A + (size_t)(m0 + rbase + l8) * KT + kbase + kt + ssrc;
        GL16(g0, (char*)As[buf] + rbase * 128 + lane * 16);
        const bft* g1 = A + (size_t)(m0 + rbase + 8 + l8) * KT + kbase + kt + ssrc;
        GL16(g1, (char*)As[buf] + rbase * 128 + 1024 + lane * 16);
    };
    auto stageB = [&](int buf, int h, int kt) {
        int rbase = 32 * w + 16 * h;
        const bft* g0 = Bt + (size_t)(n0 + rbase + l8) * KT + kbase + kt + ssrc;
        GL16(g0, (char*)Bs[buf] + rbase * 128 + lane * 16);
        const bft* g1 = Bt + (size_t)(n0 + rbase + 8 + l8) * KT + kbase + kt + ssrc;
        GL16(g1, (char*)Bs[buf] + rbase * 128 + 1024 + lane * 16);
    };
    auto ldA = [&](int buf, int mi, int kk) {
        int r = wr * 128 + mi * 16 + lrow;
        return *(const bf16x8*)((const char*)As[buf] + r * 128 + (((kk * 4 + lk) ^ (r & 7)) * 16));
    };
    auto ldB = [&](int buf, int ni, int kk) {
        int r = wc * 64 + ni * 16 + lrow;
        return *(const bf16x8*)((const char*)Bs[buf] + r * 128 + (((kk * 4 + lk) ^ (r & 7)) * 16));
    };

    f32x4 acc[8][4];
    #pragma unroll
    for (int i = 0; i < 8; ++i)
        #pragma unroll
        for (int j = 0; j < 4; ++j) acc[i][j] = (f32x4)0.f;

    stageA(0, 0, 0); stageB(0, 0, 0); stageA(0, 1, 0); stageB(0, 1, 0);
    asm volatile("s_waitcnt vmcnt(4)" ::: "memory");
    FENCE; __builtin_amdgcn_s_barrier(); FENCE;

    bf16x8 aE[4][2], aO[4][2], bE[2][2], bO[2][2];
    for (int t = 0; t < NT; ++t) {
        int cur = t & 1, nxt = cur ^ 1;
        int ktn = (t + 1) * 64;
        bool pre = (t + 1 < NT);
        #pragma unroll
        for (int i = 0; i < 4; ++i)
            #pragma unroll
            for (int kk = 0; kk < 2; ++kk) aE[i][kk] = ldA(cur, 2 * i, kk);
        #pragma unroll
        for (int j = 0; j < 2; ++j)
            #pragma unroll
            for (int kk = 0; kk < 2; ++kk) bE[j][kk] = ldB(cur, 2 * j, kk);
        if (pre) { stageA(nxt, 0, ktn); asm volatile("s_waitcnt vmcnt(2)" ::: "memory"); }
        else     {                       asm volatile("s_waitcnt vmcnt(0)" ::: "memory"); }
        FENCE; __builtin_amdgcn_s_barrier(); FENCE;
        __builtin_amdgcn_s_setprio(1);
        #pragma unroll
        for (int i = 0; i < 4; ++i)
            #pragma unroll
            for (int j = 0; j < 2; ++j)
                #pragma unroll
                for (int kk = 0; kk < 2; ++kk)
                    acc[2 * i][2 * j] = __builtin_amdgcn_mfma_f32_16x16x32_bf16(aE[i][kk], bE[j][kk], acc[2 * i][2 * j], 0, 0, 0);
        __builtin_amdgcn_s_setprio(0);
        FENCE; __builtin_amdgcn_s_barrier(); FENCE;
        #pragma unroll
        for (int j = 0; j < 2; ++j)
            #pragma unroll
            for (int kk = 0; kk < 2; ++kk) bO[j][kk] = ldB(cur, 2 * j + 1, kk);
        if (pre) stageB(nxt, 0, ktn);
        FENCE; __builtin_amdgcn_s_barrier(); FENCE;
        __builtin_amdgcn_s_setprio(1);
        #pragma unroll
        for (int i = 0; i < 4; ++i)
            #pragma unroll
            for (int j = 0; j < 2; ++j)
                #pragma unroll
                for (int kk = 0; kk < 2; ++kk)
                    acc[2 * i][2 * j + 1] = __builtin_amdgcn_mfma_f32_16x16x32_bf16(aE[i][kk], bO[j][kk], acc[2 * i][2 * j + 1], 0, 0, 0);
        __builtin_amdgcn_s_setprio(0);
        FENCE; __builtin_amdgcn_s_barrier(); FENCE;
        #pragma unroll
        for (int i = 0; i < 4; ++i)
            #pragma unroll
            for (int kk = 0; kk < 2; ++kk) aO[i][kk] = ldA(cur, 2 * i + 1, kk);
        if (pre) stageA(nxt, 1, ktn);
        FENCE; __builtin_amdgcn_s_barrier(); FENCE;
        __builtin_amdgcn_s_setprio(1);
        #pragma unroll
        for (int i = 0; i < 4; ++i)
            #pragma unroll
            for (int j = 0; j < 2; ++j)
                #pragma unroll
                for (int kk = 0; kk < 2; ++kk)
                    acc[2 * i + 1][2 * j] = __builtin_amdgcn_mfma_f32_16x16x32_bf16(aO[i][kk], bE[j][kk], acc[2 * i + 1][2 * j], 0, 0, 0);
        __builtin_amdgcn_s_setprio(0);
        FENCE; __builtin_amdgcn_s_barrier(); FENCE;
        if (pre) { stageB(nxt, 1, ktn); asm volatile("s_waitcnt vmcnt(4)" ::: "memory"); }
        FENCE; __builtin_amdgcn_s_barrier(); FENCE;
        __builtin_amdgcn_s_setprio(1);
        #pragma unroll
        for (int i = 0; i < 4; ++i)
            #pragma unroll
            for (int j = 0; j < 2; ++j)
                #pragma unroll
                for (int kk = 0; kk < 2; ++kk)
                    acc[2 * i + 1][2 * j + 1] = __builtin_amdgcn_mfma_f32_16x16x32_bf16(aO[i][kk], bO[j][kk], acc[2 * i + 1][2 * j + 1], 0, 0, 0);
        __builtin_amdgcn_s_setprio(0);
        FENCE; __builtin_amdgcn_s_barrier(); FENCE;
    }
    bft* pp = (slice == 0) ? q0 : (slice == 1) ? q1 : (slice == 2) ? q2 : q3;
    #pragma unroll
    for (int mi = 0; mi < 8; ++mi)
        #pragma unroll
        for (int ni = 0; ni < 4; ++ni)
            #pragma unroll
            for (int r = 0; r < 4; ++r) {
                int gr = m0 + wr * 128 + mi * 16 + lk * 4 + r;
                int gc = n0 + wc * 64 + ni * 16 + lrow;
                pp[(size_t)gr * N + gc] = __float2bfloat16(acc[mi][ni][r]);
            }
}

// ---------------- split-K reduce: out = x1 + b2 + sum(partials) ----------------
__global__ __launch_bounds__(256) void k_mlpred(const bft* __restrict__ q0, const bft* __restrict__ q1,
                                                const bft* __restrict__ q2, const bft* __restrict__ q3,
                                                const float* __restrict__ x1, const float* __restrict__ b2,
                                                float* __restrict__ out) {
    size_t i = ((size_t)blockIdx.x * 256 + threadIdx.x) * 8;
    bf16x8 a0 = *(const bf16x8*)(q0 + i);
    bf16x8 a1 = *(const bf16x8*)(q1 + i);
    bf16x8 a2 = *(const bf16x8*)(q2 + i);
    bf16x8 a3 = *(const bf16x8*)(q3 + i);
    int col = (int)(i & 1023);
    float4 b0 = *(const float4*)(b2 + col);
    float4 b1v = *(const float4*)(b2 + col + 4);
    float4 x0 = *(const float4*)(x1 + i);
    float4 x1v = *(const float4*)(x1 + i + 4);
    float s[8];
    #pragma unroll
    for (int j = 0; j < 8; ++j)
        s[j] = bf2f(a0[j]) + bf2f(a1[j]) + bf2f(a2[j]) + bf2f(a3[j]);
    float4 o0 = make_float4(s[0] + b0.x + x0.x, s[1] + b0.y + x0.y, s[2] + b0.z + x0.z, s[3] + b0.w + x0.w);
    float4 o1 = make_float4(s[4] + b1v.x + x1v.x, s[5] + b1v.y + x1v.y, s[6] + b1v.z + x1v.z, s[7] + b1v.w + x1v.w);
    *(float4*)(out + i) = o0;
    *(float4*)(out + i + 4) = o1;
}

// ---------------- fused KV utilities (3 launches -> 1): kvprep | cmp_kv | blockmeans ----------------
// blocks [0,256): kvprep; [256,1280): cmp_kv; [1280,1792): blockmeans. All 256 thr, block-uniform barriers.
__global__ __launch_bounds__(256) void k_kvutil(const float* __restrict__ k, const float* __restrict__ v,
                                                const float* __restrict__ q,
                                                bft* __restrict__ kb16, bft* __restrict__ vT16,
                                                bft* __restrict__ ck, bft* __restrict__ cvT,
                                                float* __restrict__ kbm, float* __restrict__ qs) {
    __shared__ float vt[64 * 65];
    __shared__ float redk[4][64], redv[4][64];
    int idx = blockIdx.x;
    int t = threadIdx.x;
    if (idx < 256) {
        // ---- kvprep: K/V -> bf16 (+V transpose) ----
        int tc = idx & 31; int kv = (idx >> 5) & 3; int b = idx >> 7;
        int ti = t >> 2, seg = t & 3, d0 = seg * 16;
        const float4* ks = (const float4*)(k + (size_t)(b * cS + tc * 64 + ti) * 256 + kv * 64 + d0);
        const float4* vs = (const float4*)(v + (size_t)(b * cS + tc * 64 + ti) * 256 + kv * 64 + d0);
        bft* kd = kb16 + ((size_t)(b * 4 + kv) * 2048 + tc * 64 + ti) * 64 + d0;
        #pragma unroll
        for (int i = 0; i < 4; ++i) {
            float4 a = ks[i];
            kd[i * 4 + 0] = __float2bfloat16(a.x); kd[i * 4 + 1] = __float2bfloat16(a.y);
            kd[i * 4 + 2] = __float2bfloat16(a.z); kd[i * 4 + 3] = __float2bfloat16(a.w);
            float4 c = vs[i];
            vt[ti * 65 + d0 + i * 4 + 0] = c.x; vt[ti * 65 + d0 + i * 4 + 1] = c.y;
            vt[ti * 65 + d0 + i * 4 + 2] = c.z; vt[ti * 65 + d0 + i * 4 + 3] = c.w;
        }
        __syncthreads();
        int d = t >> 2, ts0 = (t & 3) * 16;
        bft* vd = vT16 + ((size_t)(b * 4 + kv) * 64 + d) * 2048 + tc * 64 + ts0;
        #pragma unroll
        for (int i = 0; i < 16; ++i) vd[i] = __float2bfloat16(vt[(ts0 + i) * 65 + d]);
    } else if (idx < 1280) {
        // ---- cmp_kv: compressed K/V means -> bf16 ----
        int i2 = idx - 256;
        int n = i2 & 127; int bk = i2 >> 7; int kv = bk & 3; int b = bk >> 2;
        int jg = t >> 6, d = t & 63;
        if (n == 127) {
            if (t < 64) {
                ck[(size_t)bk * 8192 + 127 * 64 + d] = __float2bfloat16(0.f);
                cvT[(size_t)bk * 8192 + d * 128 + 127] = __float2bfloat16(0.f);
            }
            return;
        }
        float sk = 0.f, sv = 0.f;
        int base = b * cS + n * 16 + jg * 8;
        #pragma unroll
        for (int j = 0; j < 8; ++j) {
            size_t o = (size_t)(base + j) * 256 + kv * 64 + d;
            sk += k[o]; sv += v[o];
        }
        redk[jg][d] = sk; redv[jg][d] = sv;
        __syncthreads();
        if (jg == 0) {
            float tk = redk[0][d] + redk[1][d] + redk[2][d] + redk[3][d];
            float tv = redv[0][d] + redv[1][d] + redv[2][d] + redv[3][d];
            ck[(size_t)bk * 8192 + n * 64 + d] = __float2bfloat16(tk * (1.f / 32.f));
            cvT[(size_t)bk * 8192 + d * 128 + n] = __float2bfloat16(tv * (1.f / 32.f));
        }
    } else {
        // ---- blockmeans: importance inputs ----
        int i2 = idx - 1280;
        int m = i2 & 63; int kvb = i2 >> 6; int kv = kvb & 3; int b = kvb >> 2;
        int jg = t >> 6, d = t & 63;
        float sk = 0.f, sq = 0.f;
        #pragma unroll
        for (int j = 0; j < 8; ++j) {
            int row = m * 32 + jg * 8 + j;
            sk += k[(size_t)(b * cS + row) * 256 + kv * 64 + d];
            size_t tb = (size_t)(b * cS + row) * 1024 + kv * 256 + d;
            sq += q[tb] + q[tb + 64] + q[tb + 128] + q[tb + 192];
        }
        redk[jg][d] = sk; redv[jg][d] = sq;
        __syncthreads();
        if (jg == 0) {
            size_t o = ((size_t)(b * cHKV + kv) * cNB + m) * 64 + d;
            kbm[o] = (redk[0][d] + redk[1][d] + redk[2][d] + redk[3][d]) * (1.f / 32.f);
            qs[o]  = (redv[0][d] + redv[1][d] + redv[2][d] + redv[3][d]) * (1.f / 32.f);
        }
    }
}

// ---------------- fused compressed attention | top-16 (2 launches -> 1) ----------------
// blocks [0,256): cmp_attn; [256,384): topk packed 4 units/block
__global__ __launch_bounds__(256) void k_catk(const bft* __restrict__ qb16, const bft* __restrict__ ck,
                                              const bft* __restrict__ cvT, const float* __restrict__ gates,
                                              bft* __restrict__ att,
                                              const float* __restrict__ qs, const float* __restrict__ kbm,
                                              int* __restrict__ sel) {
    __shared__ __align__(16) bft Qs[256 * 64];
    __shared__ __align__(16) bft Ks[128 * 64];
    __shared__ __align__(16) bft VTs[64 * 128];
    __shared__ __align__(16) bft Ps[4 * 16 * 128];
    __shared__ float qrow4[4][64];
    int bidx = blockIdx.x;
    int tid = threadIdx.x;
    if (bidx >= 256) {
        // ---- topk: 4 wave-units per block ----
        int u = tid >> 6, lane = tid & 63;
        int idx2 = (bidx - 256) * 4 + u;
        int n = idx2 & 63; int kvb = idx2 >> 6; int kv = kvb & 3; int b = kvb >> 2;
        size_t base = (size_t)(b * cHKV + kv) * cNB;
        qrow4[u][lane] = qs[(base + n) * 64 + lane];
        __syncthreads();
        float val;
        if (lane <= n) {
            const float* kb = kbm + (base + lane) * 64;
            float s_ = 0.f;
            for (int d = 0; d < 64; ++d) s_ += qrow4[u][d] * kb[d];
            val = (lane == n) ? 1e9f : s_;
        } else val = -1e9f;
        int* so = sel + (base + n) * cTB;
        float v_ = val;
        for (int t = 0; t < cTB; ++t) {
            float bv = v_; int bi = lane;
            #pragma unroll
            for (int o = 32; o; o >>= 1) {
                float ov = __shfl_xor(bv, o); int oi = __shfl_xor(bi, o);
                if (ov > bv || (ov == bv && oi < bi)) { bv = ov; bi = oi; }
            }
            if (lane == 0) so[t] = bi;
            if (lane == bi) v_ = -INFINITY;
        }
        return;
    }
    int idx = bidx;
    int chunk = idx & 31; int bk = idx >> 5; int kv = bk & 3; int b = bk >> 2;
    // stage Q via GL16 from pre-scaled bf16 (pre-swizzled source); r in [0,256), hh in [0,4)
    #pragma unroll
    for (int c = 0; c < 8; ++c) {
        int p = c * 256 + tid; int r = p >> 3, s = p & 7;
        int hh = r >> 6, toff = r & 63;
        const bft* src = qb16 + ((size_t)(b * cS + chunk * 64 + toff)) * 1024 + (kv * 4 + hh) * 64 + ((s ^ (r & 7)) * 8);
        GL16(src, (char*)Qs + p * 16);
    }
    if (tid < 128) {
        int r = tid;
        const bf16x8* src = (const bf16x8*)(ck + (size_t)bk * 8192 + r * 64);
        #pragma unroll
        for (int s = 0; s < 8; ++s)
            *(bf16x8*)((char*)Ks + r * 128 + ((s ^ (r & 7)) * 16)) = src[s];
    }
    if (tid < 64) {
        int r = tid;
        const bf16x8* src = (const bf16x8*)(cvT + (size_t)bk * 8192 + r * 128);
        #pragma unroll
        for (int s = 0; s < 16; ++s)
            *(bf16x8*)((char*)VTs + r * 256 + ((s ^ (r & 7)) * 16)) = src[s];
    }
    __syncthreads();

    int w = tid >> 6, lane = tid & 63, lrow = lane & 15, lk = lane >> 4;
    int hg = kv * cGQ + w;
    #pragma unroll
    for (int rt = 0; rt < 4; ++rt) {
        int rowb = w * 64 + rt * 16;
        bf16x8 aq[2];
        #pragma unroll
        for (int kh = 0; kh < 2; ++kh) {
            int r = rowb + lrow;
            aq[kh] = *(const bf16x8*)((const char*)Qs + r * 128 + (((kh * 4 + lk) ^ (r & 7)) * 16));
        }
        f32x4 sa[8];
        #pragma unroll
        for (int nt = 0; nt < 8; ++nt) {
            sa[nt] = (f32x4)0.f;
            #pragma unroll
            for (int kh = 0; kh < 2; ++kh) {
                int kr = nt * 16 + lrow;
                bf16x8 bv_ = *(const bf16x8*)((const char*)Ks + kr * 128 + (((kh * 4 + lk) ^ (kr & 7)) * 16));
                sa[nt] = __builtin_amdgcn_mfma_f32_16x16x32_bf16(aq[kh], bv_, sa[nt], 0, 0, 0);
            }
        }
        float mrow[4], srow[4]; int nv[4];
        #pragma unroll
        for (int r = 0; r < 4; ++r) {
            int s_abs = chunk * 64 + rt * 16 + lk * 4 + r;
            nv[r] = (s_abs >= 31) ? (((s_abs - 31) >> 4) + 1) : 0;
            mrow[r] = -INFINITY; srow[r] = 0.f;
        }
        #pragma unroll
        for (int nt = 0; nt < 8; ++nt) {
            int key = nt * 16 + lrow;
            #pragma unroll
            for (int r = 0; r < 4; ++r) {
                float sc = sa[nt][r];   // qb16 pre-scaled by 1/8
                if (key < nv[r]) mrow[r] = fmaxf(mrow[r], sc);
            }
        }
        #pragma unroll
        for (int r = 0; r < 4; ++r) {
            #pragma unroll
            for (int o = 8; o; o >>= 1) mrow[r] = fmaxf(mrow[r], __shfl_xor(mrow[r], o));
        }
        #pragma unroll
        for (int nt = 0; nt < 8; ++nt) {
            int key = nt * 16 + lrow;
            #pragma unroll
            for (int r = 0; r < 4; ++r) {
                float sc = sa[nt][r];
                float p = (key < nv[r]) ? __expf(sc - mrow[r]) : 0.f;
                srow[r] += p;
                int rit = lk * 4 + r;
                *(bft*)((char*)Ps + w * 4096 + rit * 256 + ((((key >> 3) ^ (rit & 7))) * 16) + (key & 7) * 2) =
                    __float2bfloat16(p);
            }
        }
        #pragma unroll
        for (int r = 0; r < 4; ++r) {
            #pragma unroll
            for (int o = 8; o; o >>= 1) srow[r] += __shfl_xor(srow[r], o);
        }
        f32x4 oa[4];
        #pragma unroll
        for (int dt = 0; dt < 4; ++dt) oa[dt] = (f32x4)0.f;
        #pragma unroll
        for (int kc = 0; kc < 4; ++kc) {
            bf16x8 pa = *(const bf16x8*)((const char*)Ps + w * 4096 + lrow * 256 + (((kc * 4 + lk) ^ (lrow & 7)) * 16));
            #pragma unroll
            for (int dt = 0; dt < 4; ++dt) {
                int vr = dt * 16 + lrow;
                bf16x8 vb = *(const bf16x8*)((const char*)VTs + vr * 256 + (((kc * 4 + lk) ^ (vr & 7)) * 16));
                oa[dt] = __builtin_amdgcn_mfma_f32_16x16x32_bf16(pa, vb, oa[dt], 0, 0, 0);
            }
        }
        float inv[4]; int toks[4];
        #pragma unroll
        for (int r = 0; r < 4; ++r) {
            int tok = chunk * 64 + rt * 16 + lk * 4 + r;
            toks[r] = tok;
            float g0 = gates[((size_t)(b * cS + tok)) * 48 + hg * 3 + 0];
            inv[r] = (srow[r] > 0.f) ? (g0 / srow[r]) : 0.f;
        }
        #pragma unroll
        for (int dt = 0; dt < 4; ++dt)
            #pragma unroll
            for (int r = 0; r < 4; ++r)
                att[((size_t)(b * cS + toks[r])) * 1024 + hg * 64 + dt * 16 + lrow] = __float2bfloat16(oa[dt][r] * inv[r]);
    }
}

// ---------------- fused selected + window attention: KVBLK=32, swapped QK^T, packed P,
// ---------------- triple-buffered K/V, counted-vmcnt pipeline. 1024 blocks x 128 thr (head-pair split):
// ---------------- 4 independent 2-wave blocks/CU + balanced n-mix quadrant mapping ----------------
__global__ __launch_bounds__(128) void k_selwin(const bft* __restrict__ qb16, const bft* __restrict__ kb16,
                                                const bft* __restrict__ vT16, const int* __restrict__ sel,
                                                const float* __restrict__ gates, const bft* __restrict__ attb,
                                                bft* __restrict__ att16) {
    __shared__ __align__(16) bft Qs[64 * 64];
    __shared__ __align__(16) bft Ks[3][32 * 64];
    __shared__ __align__(16) bft Vs[3][64 * 32];
    __shared__ __align__(16) bft Ps[2][32 * 32];
    __shared__ int msL[40];
    __shared__ int nmS[2];
    // balanced bijective decode: quadrant q=(b,hp), group g=(kv,t); n = t or 63-t by quadrant
    int raw = blockIdx.x;
    int q_ = raw >> 8, g_ = raw & 255;
    int kv = g_ >> 6, t_ = g_ & 63;
    int n = ((q_ == 1) || (q_ == 2)) ? (63 - t_) : t_;
    int b = q_ >> 1, hp = q_ & 1;
    int bkv = b * 4 + kv;
    int tid = threadIdx.x;
    int w = tid >> 6, lane = tid & 63, lrow = lane & 15, lk = lane >> 4;
    int h = kv * 4 + hp * 2 + w;

    // stage Q: 64 rows (2 heads x 32 tokens) x 8 slots = 512 positions, 128 thr x 4 iters
    #pragma unroll
    for (int c = 0; c < 4; ++c) {
        int p = c * 128 + tid; int r = p >> 3, s = p & 7;
        const bft* src = qb16 + ((size_t)(b * cS + n * 32 + (r & 31))) * 1024 + (kv * 4 + hp * 2 + (r >> 5)) * 64 + ((s ^ (r & 7)) * 8);
        GL16(src, (char*)Qs + p * 16);
    }
    // stage K0/V0: 256 positions each, 128 thr x 2 iters
    #pragma unroll
    for (int it = 0; it < 2; ++it) {
        int p = it * 128 + tid;
        int row = p >> 3, s = p & 7;
        const bft* srck = kb16 + ((size_t)bkv * 2048 + n * 32 + row) * 64 + ((s ^ (row & 7)) * 8);
        GL16(srck, (char*)Ks[0] + p * 16);
        int rowv = p >> 2, g3 = p & 3;
        const bft* srcv = vT16 + ((size_t)bkv * 64 + rowv) * 2048 + n * 32 + ((g3 ^ (rowv & 3)) * 8);
        GL16(srcv, (char*)Vs[0] + p * 16);
    }
    if (tid == 0) {
        const int* selp = sel + ((size_t)bkv * cNB + n) * cTB;
        int nm = 0;
        #pragma unroll
        for (int t = 0; t < cTB; ++t) { int m = selp[t]; if (m <= n) msL[nm++] = m; }
        nmS[0] = nm;
        int m0 = (n > 16) ? (n - 16) : 0;
        for (int m = m0; m <= n; ++m) msL[nm++] = m;
        nmS[1] = nm;
    }
    // FULL drain (vmcnt AND lgkmcnt) before cross-wave read of msL/nmS.
    __syncthreads();

    int p1 = nmS[0], nm = nmS[1];
    bf16x8 qf[2][2];
    #pragma unroll
    for (int qt = 0; qt < 2; ++qt)
        #pragma unroll
        for (int kh = 0; kh < 2; ++kh) {
            int r = w * 32 + qt * 16 + lrow;
            qf[qt][kh] = *(const bf16x8*)((const char*)Qs + r * 128 + (((kh * 4 + lk) ^ (r & 7)) * 16));
        }

    f32x4 oa[2][4], accf[2][4];
    float sacc[2] = {0.f, 0.f};
    #pragma unroll
    for (int qt = 0; qt < 2; ++qt)
        #pragma unroll
        for (int dt = 0; dt < 4; ++dt) { oa[qt][dt] = (f32x4)0.f; accf[qt][dt] = (f32x4)0.f; }

    for (int i = 0; i < nm; ++i) {
        int buf = i % 3;
        if (i == 0 && nm > 1) {
            int m1 = msL[1];
            #pragma unroll
            for (int it = 0; it < 2; ++it) {
                int p = it * 128 + tid;
                int row = p >> 3, s = p & 7;
                const bft* srck = kb16 + ((size_t)bkv * 2048 + m1 * 32 + row) * 64 + ((s ^ (row & 7)) * 8);
                GL16(srck, (char*)Ks[1] + p * 16);
                int rowv = p >> 2, g3 = p & 3;
                const bft* srcv = vT16 + ((size_t)bkv * 64 + rowv) * 2048 + m1 * 32 + ((g3 ^ (rowv & 3)) * 8);
                GL16(srcv, (char*)Vs[1] + p * 16);
            }
        }
        if (i + 2 < nm) {
            int m2 = msL[i + 2]; int sl = (i + 2) % 3;
            #pragma unroll
            for (int it = 0; it < 2; ++it) {
                int p = it * 128 + tid;
                int row = p >> 3, s = p & 7;
                const bft* srck = kb16 + ((size_t)bkv * 2048 + m2 * 32 + row) * 64 + ((s ^ (row & 7)) * 8);
                GL16(srck, (char*)Ks[sl] + p * 16);
                int rowv = p >> 2, g3 = p & 3;
                const bft* srcv = vT16 + ((size_t)bkv * 64 + rowv) * 2048 + m2 * 32 + ((g3 ^ (rowv & 3)) * 8);
                GL16(srcv, (char*)Vs[sl] + p * 16);
            }
        }
        int m = msL[i];
        bool diag = (m == n);
        #pragma unroll
        for (int qt = 0; qt < 2; ++qt) {
            int q = qt * 16 + lrow;
            #pragma unroll
            for (int kt = 0; kt < 2; ++kt) {
                f32x4 a = (f32x4)0.f;
                #pragma unroll
                for (int kh = 0; kh < 2; ++kh) {
                    int kr = kt * 16 + lrow;
                    bf16x8 ak = *(const bf16x8*)((const char*)Ks[buf] + kr * 128 + (((kh * 4 + lk) ^ (kr & 7)) * 16));
                    a = __builtin_amdgcn_mfma_f32_16x16x32_bf16(ak, qf[qt][kh], a, 0, 0, 0);
                }
                int k0 = kt * 16 + lk * 4;
                float p0 = (!diag || k0 <= q)     ? __expf(a[0]) : 0.f;
                float p1v = (!diag || k0 + 1 <= q) ? __expf(a[1]) : 0.f;
                float p2 = (!diag || k0 + 2 <= q) ? __expf(a[2]) : 0.f;
                float p3 = (!diag || k0 + 3 <= q) ? __expf(a[3]) : 0.f;
                sacc[qt] += p0 + p1v + p2 + p3;
                bft h0 = __float2bfloat16(p0), h1 = __float2bfloat16(p1v);
                bft h2 = __float2bfloat16(p2), h3 = __float2bfloat16(p3);
                unsigned int w0 = ((unsigned int)(*(unsigned short*)&h1) << 16) | (unsigned int)(*(unsigned short*)&h0);
                unsigned int w1 = ((unsigned int)(*(unsigned short*)&h3) << 16) | (unsigned int)(*(unsigned short*)&h2);
                int g = kt * 2 + (lk >> 1);
                *(uint2*)((char*)Ps[w] + q * 64 + ((g ^ (q & 3)) * 16) + (lk & 1) * 8) = make_uint2(w0, w1);
            }
        }
        #pragma unroll
        for (int qt = 0; qt < 2; ++qt) {
            int q = qt * 16 + lrow;
            bf16x8 pa = *(const bf16x8*)((const char*)Ps[w] + q * 64 + ((lk ^ (q & 3)) * 16));
            #pragma unroll
            for (int dt = 0; dt < 4; ++dt) {
                int vr = dt * 16 + lrow;
                bf16x8 vb = *(const bf16x8*)((const char*)Vs[buf] + vr * 64 + ((lk ^ (vr & 3)) * 16));
                oa[qt][dt] = __builtin_amdgcn_mfma_f32_16x16x32_bf16(pa, vb, oa[qt][dt], 0, 0, 0);
            }
        }
        if (i == p1 - 1 || i == nm - 1) {
            int gi = (i == p1 - 1) ? 1 : 2;
            #pragma unroll
            for (int qt = 0; qt < 2; ++qt) {
                float s2 = sacc[qt];
                s2 += __shfl_xor(s2, 16); s2 += __shfl_xor(s2, 32);
                #pragma unroll
                for (int r = 0; r < 4; ++r) {
                    float l = __shfl(s2, lk * 4 + r);
                    int tok = n * 32 + qt * 16 + lk * 4 + r;
                    float g = gates[((size_t)(b * cS + tok)) * 48 + h * 3 + gi];
                    float f = g / l;
                    #pragma unroll
                    for (int dt = 0; dt < 4; ++dt) accf[qt][dt][r] += f * oa[qt][dt][r];
                }
                sacc[qt] = 0.f;
                #pragma unroll
                for (int dt = 0; dt < 4; ++dt) oa[qt][dt] = (f32x4)0.f;
            }
        }
        if (i + 1 < nm) {
            if (i + 2 < nm) { asm volatile("s_waitcnt vmcnt(4)" ::: "memory"); }
            else            { asm volatile("s_waitcnt vmcnt(0)" ::: "memory"); }
            FENCE; __builtin_amdgcn_s_barrier(); FENCE;
        }
    }
    #pragma unroll
    for (int qt = 0; qt < 2; ++qt)
        #pragma unroll
        for (int dt = 0; dt < 4; ++dt)
            #pragma unroll
            for (int r = 0; r < 4; ++r) {
                int tok = n * 32 + qt * 16 + lk * 4 + r;
                size_t a_ = ((size_t)(b * cS + tok)) * 1024 + h * 64 + dt * 16 + lrow;
                att16[a_] = __float2bfloat16(__bfloat162float(attb[a_]) + accf[qt][dt][r]);
            }
}

extern "C" void kernel_launch(void* const* d_in, const int* in_sizes, int n_in,
                              void* d_out, int out_size, void* d_ws, size_t ws_size,
                              hipStream_t stream) {
    const float* x    = (const float*)d_in[0];
    const float* ln1w = (const float*)d_in[1];
    const float* ln1b = (const float*)d_in[2];
    const float* wq   = (const float*)d_in[3];
    const float* bq   = (const float*)d_in[4];
    const float* wk   = (const float*)d_in[5];
    const float* bk   = (const float*)d_in[6];
    const float* wv   = (const float*)d_in[7];
    const float* bv   = (const float*)d_in[8];
    const float* wg   = (const float*)d_in[9];
    const float* bg   = (const float*)d_in[10];
    const float* wo   = (const float*)d_in[11];
    const float* bo   = (const float*)d_in[12];
    const float* ln2w = (const float*)d_in[13];
    const float* ln2b = (const float*)d_in[14];
    const float* w1   = (const float*)d_in[15];
    const float* b1   = (const float*)d_in[16];
    const float* w2   = (const float*)d_in[17];
    const float* b2   = (const float*)d_in[18];

    char* ws = (char*)d_ws;
    const size_t MiB = 1024 * 1024;
    bft*  wcatT = (bft*) (ws);                        // [1664][1024]
    bft*  woT   = (bft*) (ws + 3 * MiB + 256 * 1024); // [1024][1024]
    bft*  w1T   = (bft*) (ws + 5 * MiB + 256 * 1024); // [4096][1024]
    bft*  w2T   = (bft*) (ws + 13 * MiB + 256 * 1024);// [1024][4096]
    bft*  hbuf  = (bft*) (ws + 21 * MiB + 256 * 1024);// [4096][1024] bf16 (LN1/LN2 out; dead during attn)
    float* qbuf = (float*)(ws + 29 * MiB + 256 * 1024);// [4096][1024]
    float* kbuf = (float*)(ws + 45 * MiB + 256 * 1024);// [4096][256]
    float* vbuf = (float*)(ws + 49 * MiB + 256 * 1024);// [4096][256]
    float* gbuf = (float*)(ws + 53 * MiB + 256 * 1024);// [4096][48]
    bft*  ckb   = (bft*)  (ws + 55 * MiB + 256 * 1024);// [8][128][64] bf16
    bft*  cvTb  = (bft*)  (ws + 56 * MiB + 256 * 1024);// [8][64][128] bf16
    float* kbmb = (float*)(ws + 57 * MiB + 256 * 1024);
    float* qsb  = (float*)(ws + 57 * MiB + 384 * 1024);
    int*   selb = (int*)  (ws + 57 * MiB + 512 * 1024);
    bft*  attb16= (bft*) (ws + 58 * MiB);             // [4096][1024] bf16 (g0*oc)
    bft*  att16 = (bft*) (ws + 74 * MiB);             // [4096][1024] bf16
    float* x1b  = (float*)(ws + 82 * MiB);            // [4096][1024] f32
    bft*  zbuf  = (bft*) (ws + 29 * MiB + 256 * 1024);// [4096][4096] bf16, aliases dead qkv region
    bft*  kb16  = (bft*) (ws + 21 * MiB + 256 * 1024);// [8][2048][64] bf16, 2 MiB
    bft*  vT16  = (bft*) (ws + 23 * MiB + 256 * 1024);// [8][64][2048] bf16, 2 MiB
    bft*  qb16  = (bft*) (ws + 82 * MiB);             // [4096][1024] bf16 prescaled, aliases x1b (dead until wo-GEMM)
    // split-K partials for MLP-down: 4 x 8 MiB bf16, placed in regions dead at MLP-down time
    bft*  skp0  = (bft*) (ws);                         // over wcatT/woT/w1T head (dead)
    bft*  skp1  = (bft*) (ws + 21 * MiB + 256 * 1024); // over hbuf (dead after MLP-up)
    bft*  skp2  = (bft*) (ws + 61 * MiB + 256 * 1024); // over attb tail (dead)
    bft*  skp3  = (bft*) (ws + 69 * MiB + 256 * 1024); // over attb/att16 tail (dead)

    // mega-prologue: LN1 + all weight transposes in one launch
    k_prolog<<<14976, 256, 0, stream>>>(x, ln1w, ln1b, hbuf, wq, wk, wv, wg, wcatT, wo, w1, w2, woT, w1T, w2T);
    k_gemm<0><<<dim3(13, 32), 256, 0, stream>>>(hbuf, wcatT, 4096, 1664, 1024,
        nullptr, nullptr, nullptr, nullptr, qbuf, kbuf, vbuf, gbuf, bq, bk, bv, bg, qb16);
    // fused KV utilities: kvprep | cmp_kv | blockmeans
    k_kvutil<<<1792, 256, 0, stream>>>(kbuf, vbuf, qbuf, kb16, vT16, ckb, cvTb, kbmb, qsb);
    // fused compressed attention | topk
    k_catk<<<384, 256, 0, stream>>>(qb16, ckb, cvTb, gbuf, attb16, qsb, kbmb, selb);
    k_selwin<<<1024, 128, 0, stream>>>(qb16, kb16, vT16, selb, gbuf, attb16, att16);
    k_gemm<1><<<dim3(8, 32), 256, 0, stream>>>(att16, woT, 4096, 1024, 1024,
        bo, x, x1b, nullptr, nullptr, nullptr, nullptr, nullptr, nullptr, nullptr, nullptr, nullptr, nullptr);
    k_ln<<<4096, 256, 0, stream>>>(x1b, ln2w, ln2b, hbuf);
    // MLP up + GELU: 256^2 8-phase kernel
    k_gemm256_gelu<<<dim3(16, 16), 512, 0, stream>>>(hbuf, w1T, b1, zbuf);
    // MLP down: split-K x4 256^2 8-phase + fused reduce (bias + residual)
    k_gemm256_sk<<<256, 512, 0, stream>>>(zbuf, w2T, skp0, skp1, skp2, skp3);
    k_mlpred<<<2048, 256, 0, stream>>>(skp0, skp1, skp2, skp3, x1b, b2, (float*)d_out);
}